// Round 1
// baseline (2387.527 us; speedup 1.0000x reference)
//
#include <hip/hip_runtime.h>
#include <hip/hip_bf16.h>
#include <math.h>

#define S_LEN 4096
#define DMODEL 768
#define NH 12
#define HD 64

// ---------------- RoPE trig table (double precision on device) ----------------
__global__ void k_build_trig(float* __restrict__ ct, float* __restrict__ st) {
  const int s = blockIdx.x;
  const int d = threadIdx.x;          // 0..63
  const int j = d & 31;               // emb = concat([freqs, freqs])
  const double inv = pow(10000.0, -(double)j / 32.0);
  const double a = (double)s * inv;
  ct[s * HD + d] = (float)cos(a);
  st[s * HD + d] = (float)sin(a);
}

// ---------------- QKV GEMM 128x128x8 + bias + RoPE + scatter ----------------
// X:[4096][768], W:[768][2304]. Writes q/k/v as [H][S][hd], RoPE applied to q,k.
__global__ __launch_bounds__(256) void k_gemm_qkv(
    const float* __restrict__ X, const float* __restrict__ W,
    const float* __restrict__ bias, const float* __restrict__ ct,
    const float* __restrict__ st, float* __restrict__ qb,
    float* __restrict__ kb, float* __restrict__ vb) {
  __shared__ float As[8][132];   // [k][m], stride 132 (528B = 33*16B, b128-aligned)
  __shared__ float Bs[8][132];   // [k][n]
  const int t = threadIdx.x;
  const int m0 = blockIdx.y * 128;
  const int n0 = blockIdx.x * 128;
  const int ty = t >> 4, tx = t & 15;
  float acc[8][8];
#pragma unroll
  for (int i = 0; i < 8; ++i)
#pragma unroll
    for (int j = 0; j < 8; ++j) acc[i][j] = 0.f;

  const int ar = t >> 1, ak = (t & 1) << 2;     // A: 2 threads/row, float4 each
  const int br = t >> 5, bc = (t & 31) << 2;    // B: 32 threads/row, float4 each

  for (int k0 = 0; k0 < DMODEL; k0 += 8) {
    const float4 a4 = *(const float4*)(X + (size_t)(m0 + ar) * DMODEL + k0 + ak);
    const float4 b4 = *(const float4*)(W + (size_t)(k0 + br) * (3 * DMODEL) + n0 + bc);
    __syncthreads();
    As[ak + 0][ar] = a4.x; As[ak + 1][ar] = a4.y;
    As[ak + 2][ar] = a4.z; As[ak + 3][ar] = a4.w;
    *(float4*)&Bs[br][bc] = b4;
    __syncthreads();
#pragma unroll
    for (int kk = 0; kk < 8; ++kk) {
      const float4 a0 = *(const float4*)&As[kk][ty * 8];
      const float4 a1 = *(const float4*)&As[kk][ty * 8 + 4];
      const float4 b0 = *(const float4*)&Bs[kk][tx * 8];
      const float4 b1 = *(const float4*)&Bs[kk][tx * 8 + 4];
      const float av[8] = {a0.x, a0.y, a0.z, a0.w, a1.x, a1.y, a1.z, a1.w};
      const float bv[8] = {b0.x, b0.y, b0.z, b0.w, b1.x, b1.y, b1.z, b1.w};
#pragma unroll
      for (int i = 0; i < 8; ++i)
#pragma unroll
        for (int j = 0; j < 8; ++j) acc[i][j] += av[i] * bv[j];
    }
  }
  // epilogue: bias + RoPE (q,k) + scatter to [H][S][hd]
#pragma unroll
  for (int i = 0; i < 8; ++i) {
    const int s = m0 + ty * 8 + i;
#pragma unroll
    for (int j = 0; j < 8; j += 2) {
      const int n = n0 + tx * 8 + j;
      float v0 = acc[i][j] + bias[n];
      float v1 = acc[i][j + 1] + bias[n + 1];
      const int cidx = n / DMODEL;            // 0:q 1:k 2:v
      const int rem = n - cidx * DMODEL;
      const int hh = rem >> 6;
      const int d = rem & 63;                 // even
      float* dst = (cidx == 0) ? qb : ((cidx == 1) ? kb : vb);
      if (cidx < 2) {
        const float c0 = ct[s * HD + d],     s0v = st[s * HD + d];
        const float c1 = ct[s * HD + d + 1], s1v = st[s * HD + d + 1];
        const float o0 = v0 * c0 - v1 * s0v;  // q'[2i]   = q[2i]cos - q[2i+1]sin
        const float o1 = v1 * c1 + v0 * s1v;  // q'[2i+1] = q[2i+1]cos + q[2i]sin
        v0 = o0; v1 = o1;
      }
      float* p = dst + (((size_t)hh * S_LEN + s) << 6) + d;
      p[0] = v0; p[1] = v1;
    }
  }
}

// ---------------- flash attention, fp32 vector ----------------
// grid (S/16, H), 256 threads. thread (r=t/16, c=t%15): row s0+r, j=c+16jj, d=c*4..+3
__global__ __launch_bounds__(256) void k_attn(
    const float* __restrict__ qb, const float* __restrict__ kb,
    const float* __restrict__ vb, float* __restrict__ ctx) {
  const int h = blockIdx.y;
  const int s0 = blockIdx.x << 4;
  const int t = threadIdx.x;
  const int r = t >> 4, c = t & 15;
  __shared__ float4 Ks4[64 * 16];   // swizzled: row j, d4 stored at slot d4^(j&15)
  __shared__ float4 Vs4[64 * 16];

  // Q row in registers (constant across all k-tiles)
  float4 q[16];
  {
    const float* qrow = qb + (((size_t)h * S_LEN + s0 + r) << 6);
#pragma unroll
    for (int i = 0; i < 16; ++i) q[i] = *(const float4*)(qrow + (i << 2));
  }
  float m = -3.0e30f, l = 0.f;
  float4 o = make_float4(0.f, 0.f, 0.f, 0.f);
  const int lj = t >> 2, ldg = t & 3;
  const float* kbase = kb + (((size_t)h * S_LEN) << 6);
  const float* vbase = vb + (((size_t)h * S_LEN) << 6);

  for (int kt = 0; kt < 64; ++kt) {
#pragma unroll
    for (int i = 0; i < 4; ++i) {
      const int d4 = ldg + (i << 2);
      const size_t goff = (((size_t)(kt << 6) + lj) << 6) + (d4 << 2);
      Ks4[lj * 16 + (d4 ^ (lj & 15))] = *(const float4*)(kbase + goff);
      Vs4[lj * 16 + (d4 ^ (lj & 15))] = *(const float4*)(vbase + goff);
    }
    __syncthreads();
    // QK^T: 4 scores per thread
    float sc[4] = {0.f, 0.f, 0.f, 0.f};
#pragma unroll
    for (int d4 = 0; d4 < 16; ++d4) {
      const float4 q4 = q[d4];
#pragma unroll
      for (int jj = 0; jj < 4; ++jj) {
        const int j = c + (jj << 4);
        const float4 k4 = Ks4[j * 16 + (d4 ^ c)];
        sc[jj] += q4.x * k4.x + q4.y * k4.y + q4.z * k4.z + q4.w * k4.w;
      }
    }
#pragma unroll
    for (int jj = 0; jj < 4; ++jj) sc[jj] *= 0.125f;  // 1/sqrt(64)
    // online softmax (row group = 16 contiguous lanes)
    float pm = fmaxf(fmaxf(sc[0], sc[1]), fmaxf(sc[2], sc[3]));
#pragma unroll
    for (int mask = 1; mask < 16; mask <<= 1) pm = fmaxf(pm, __shfl_xor(pm, mask, 64));
    const float mn = fmaxf(m, pm);
    const float corr = expf(m - mn);
    float p[4]; float rs = 0.f;
#pragma unroll
    for (int jj = 0; jj < 4; ++jj) { p[jj] = expf(sc[jj] - mn); rs += p[jj]; }
#pragma unroll
    for (int mask = 1; mask < 16; mask <<= 1) rs += __shfl_xor(rs, mask, 64);
    l = l * corr + rs;
    m = mn;
    o.x *= corr; o.y *= corr; o.z *= corr; o.w *= corr;
    // PV: o[d=c*4..+3] += sum_j p_j * V[j][d]; p_j fetched via shfl
#pragma unroll
    for (int jj = 0; jj < 4; ++jj) {
#pragma unroll
      for (int jl = 0; jl < 16; ++jl) {
        const int j = (jj << 4) + jl;
        const float pj = __shfl(p[jj], (t & 48) | jl, 64);
        const float4 v4 = Vs4[j * 16 + (c ^ jl)];
        o.x += pj * v4.x; o.y += pj * v4.y; o.z += pj * v4.z; o.w += pj * v4.w;
      }
    }
    __syncthreads();
  }
  const float inv = 1.0f / l;
  float4 res = make_float4(o.x * inv, o.y * inv, o.z * inv, o.w * inv);
  *(float4*)(ctx + (size_t)(s0 + r) * DMODEL + (h << 6) + (c << 2)) = res;
}

// ---------------- output projection GEMM 128x128x8 + bias ----------------
__global__ __launch_bounds__(256) void k_gemm_out(
    const float* __restrict__ Xc, const float* __restrict__ W,
    const float* __restrict__ bias, float* __restrict__ out) {
  __shared__ float As[8][132];
  __shared__ float Bs[8][132];
  const int t = threadIdx.x;
  const int m0 = blockIdx.y * 128;
  const int n0 = blockIdx.x * 128;
  const int ty = t >> 4, tx = t & 15;
  float acc[8][8];
#pragma unroll
  for (int i = 0; i < 8; ++i)
#pragma unroll
    for (int j = 0; j < 8; ++j) acc[i][j] = 0.f;

  const int ar = t >> 1, ak = (t & 1) << 2;
  const int br = t >> 5, bc = (t & 31) << 2;

  for (int k0 = 0; k0 < DMODEL; k0 += 8) {
    const float4 a4 = *(const float4*)(Xc + (size_t)(m0 + ar) * DMODEL + k0 + ak);
    const float4 b4 = *(const float4*)(W + (size_t)(k0 + br) * DMODEL + n0 + bc);
    __syncthreads();
    As[ak + 0][ar] = a4.x; As[ak + 1][ar] = a4.y;
    As[ak + 2][ar] = a4.z; As[ak + 3][ar] = a4.w;
    *(float4*)&Bs[br][bc] = b4;
    __syncthreads();
#pragma unroll
    for (int kk = 0; kk < 8; ++kk) {
      const float4 a0 = *(const float4*)&As[kk][ty * 8];
      const float4 a1 = *(const float4*)&As[kk][ty * 8 + 4];
      const float4 b0 = *(const float4*)&Bs[kk][tx * 8];
      const float4 b1 = *(const float4*)&Bs[kk][tx * 8 + 4];
      const float av[8] = {a0.x, a0.y, a0.z, a0.w, a1.x, a1.y, a1.z, a1.w};
      const float bv[8] = {b0.x, b0.y, b0.z, b0.w, b1.x, b1.y, b1.z, b1.w};
#pragma unroll
      for (int i = 0; i < 8; ++i)
#pragma unroll
        for (int j = 0; j < 8; ++j) acc[i][j] += av[i] * bv[j];
    }
  }
#pragma unroll
  for (int i = 0; i < 8; ++i) {
    const int s = m0 + ty * 8 + i;
    const int n = n0 + tx * 8;
    float4 r0, r1;
    r0.x = acc[i][0] + bias[n + 0]; r0.y = acc[i][1] + bias[n + 1];
    r0.z = acc[i][2] + bias[n + 2]; r0.w = acc[i][3] + bias[n + 3];
    r1.x = acc[i][4] + bias[n + 4]; r1.y = acc[i][5] + bias[n + 5];
    r1.z = acc[i][6] + bias[n + 6]; r1.w = acc[i][7] + bias[n + 7];
    *(float4*)(out + (size_t)s * DMODEL + n) = r0;
    *(float4*)(out + (size_t)s * DMODEL + n + 4) = r1;
  }
}

extern "C" void kernel_launch(void* const* d_in, const int* in_sizes, int n_in,
                              void* d_out, int out_size, void* d_ws, size_t ws_size,
                              hipStream_t stream) {
  const float* x    = (const float*)d_in[0];
  const float* Wqkv = (const float*)d_in[1];
  const float* bqkv = (const float*)d_in[2];
  const float* Wout = (const float*)d_in[3];
  const float* bout = (const float*)d_in[4];
  float* out = (float*)d_out;
  float* ws = (float*)d_ws;

  const size_t NQ = (size_t)NH * S_LEN * HD;     // 3,145,728 floats per tensor
  float* qb = ws;
  float* kb = qb + NQ;
  float* vb = kb + NQ;
  float* cx = vb + NQ;                            // [S][D]
  float* ct = cx + (size_t)S_LEN * DMODEL;        // [S][HD]
  float* st = ct + (size_t)S_LEN * HD;

  k_build_trig<<<dim3(S_LEN), dim3(64), 0, stream>>>(ct, st);
  k_gemm_qkv<<<dim3((3 * DMODEL) / 128, S_LEN / 128), dim3(256), 0, stream>>>(
      x, Wqkv, bqkv, ct, st, qb, kb, vb);
  k_attn<<<dim3(S_LEN / 16, NH), dim3(256), 0, stream>>>(qb, kb, vb, cx);
  k_gemm_out<<<dim3(DMODEL / 128, S_LEN / 128), dim3(256), 0, stream>>>(
      cx, Wout, bout, out);
}

// Round 2
// 609.228 us; speedup vs baseline: 3.9189x; 3.9189x over previous
//
#include <hip/hip_runtime.h>
#include <hip/hip_bf16.h>
#include <math.h>

#define S_LEN 4096
#define DMODEL 768
#define NH 12
#define HD 64

using f32x4 = __attribute__((ext_vector_type(4))) float;
using s16x8 = __attribute__((ext_vector_type(8))) short;

__device__ inline ushort f2bf(float f) {
  union { float f; uint32_t u; } v; v.f = f;
  uint32_t r = v.u + 0x7fffu + ((v.u >> 16) & 1u);   // RTNE
  return (ushort)(r >> 16);
}
__device__ inline float bf2f(ushort u) {
  union { uint32_t u; float f; } v; v.u = ((uint32_t)u) << 16;
  return v.f;
}

// scale folded into q: 1/sqrt(64) * log2(e)  -> softmax uses exp2
#define QSCL 0.18033688011112042f

// ---------------- RoPE trig table (double precision on device) ----------------
__global__ void k_build_trig(float* __restrict__ ct, float* __restrict__ st) {
  const int s = blockIdx.x;
  const int d = threadIdx.x;          // 0..63
  const int j = d & 31;
  const double inv = pow(10000.0, -(double)j / 32.0);
  const double a = (double)s * inv;
  ct[s * HD + d] = (float)cos(a);
  st[s * HD + d] = (float)sin(a);
}

// ---------------- QKV GEMM 128x128x8 + bias + RoPE + split-bf16 scatter ------
// Writes q_hi/q_lo (RoPE, *QSCL), k_hi/k_lo (RoPE) as [H][S][64] bf16,
// and V transposed vt[H][64][S] bf16.
__global__ __launch_bounds__(256) void k_gemm_qkv(
    const float* __restrict__ X, const float* __restrict__ W,
    const float* __restrict__ bias, const float* __restrict__ ct,
    const float* __restrict__ st, ushort* __restrict__ qh,
    ushort* __restrict__ ql, ushort* __restrict__ kh,
    ushort* __restrict__ kl, ushort* __restrict__ vt) {
  __shared__ float As[8][132];
  __shared__ float Bs[8][132];
  const int t = threadIdx.x;
  const int m0 = blockIdx.y * 128;
  const int n0 = blockIdx.x * 128;
  const int ty = t >> 4, tx = t & 15;
  float acc[8][8];
#pragma unroll
  for (int i = 0; i < 8; ++i)
#pragma unroll
    for (int j = 0; j < 8; ++j) acc[i][j] = 0.f;

  const int ar = t >> 1, ak = (t & 1) << 2;
  const int br = t >> 5, bc = (t & 31) << 2;

  for (int k0 = 0; k0 < DMODEL; k0 += 8) {
    const float4 a4 = *(const float4*)(X + (size_t)(m0 + ar) * DMODEL + k0 + ak);
    const float4 b4 = *(const float4*)(W + (size_t)(k0 + br) * (3 * DMODEL) + n0 + bc);
    __syncthreads();
    As[ak + 0][ar] = a4.x; As[ak + 1][ar] = a4.y;
    As[ak + 2][ar] = a4.z; As[ak + 3][ar] = a4.w;
    *(float4*)&Bs[br][bc] = b4;
    __syncthreads();
#pragma unroll
    for (int kk = 0; kk < 8; ++kk) {
      const float4 a0 = *(const float4*)&As[kk][ty * 8];
      const float4 a1 = *(const float4*)&As[kk][ty * 8 + 4];
      const float4 b0 = *(const float4*)&Bs[kk][tx * 8];
      const float4 b1 = *(const float4*)&Bs[kk][tx * 8 + 4];
      const float av[8] = {a0.x, a0.y, a0.z, a0.w, a1.x, a1.y, a1.z, a1.w};
      const float bv[8] = {b0.x, b0.y, b0.z, b0.w, b1.x, b1.y, b1.z, b1.w};
#pragma unroll
      for (int i = 0; i < 8; ++i)
#pragma unroll
        for (int j = 0; j < 8; ++j) acc[i][j] += av[i] * bv[j];
    }
  }

  const int cidx = n0 / DMODEL;   // uniform per block (128 | 768)
  if (cidx < 2) {                 // q or k: bias + RoPE + hi/lo split
    ushort* dh = (cidx == 0) ? qh : kh;
    ushort* dl = (cidx == 0) ? ql : kl;
    const float scl = (cidx == 0) ? QSCL : 1.0f;
#pragma unroll
    for (int i = 0; i < 8; ++i) {
      const int s = m0 + ty * 8 + i;
#pragma unroll
      for (int j = 0; j < 8; j += 2) {
        const int n = n0 + tx * 8 + j;
        const int rem = n - cidx * DMODEL;
        const int hh = rem >> 6;
        const int d = rem & 63;
        const float v0 = acc[i][j] + bias[n];
        const float v1 = acc[i][j + 1] + bias[n + 1];
        const float c0 = ct[s * HD + d],     s0v = st[s * HD + d];
        const float c1 = ct[s * HD + d + 1], s1v = st[s * HD + d + 1];
        const float o0 = (v0 * c0 - v1 * s0v) * scl;
        const float o1 = (v1 * c1 + v0 * s1v) * scl;
        const ushort h0 = f2bf(o0), h1 = f2bf(o1);
        const ushort l0 = f2bf(o0 - bf2f(h0)), l1 = f2bf(o1 - bf2f(h1));
        const size_t off = (((size_t)hh * S_LEN + s) << 6) + d;
        *(ushort2*)(dh + off) = make_ushort2(h0, h1);
        *(ushort2*)(dl + off) = make_ushort2(l0, l1);
      }
    }
  } else {                        // v: bias + transpose-pack to vt[h][d][s]
#pragma unroll
    for (int j = 0; j < 8; ++j) {
      const int n = n0 + tx * 8 + j;
      const int rem = n - 2 * DMODEL;
      const int hh = rem >> 6;
      const int d = rem & 63;
      const float bb = bias[n];
      union { ushort us[8]; float4 f4; } u;
#pragma unroll
      for (int i = 0; i < 8; ++i) u.us[i] = f2bf(acc[i][j] + bb);
      *(float4*)(vt + ((size_t)hh * 64 + d) * S_LEN + m0 + ty * 8) = u.f4;
    }
  }
}

// ---------------- flash attention, split-bf16 MFMA ----------------
// grid (S/64, H), 256 threads = 4 waves; wave w owns q-rows s0+16w..+15.
__global__ __launch_bounds__(256) void k_attn_mfma(
    const ushort* __restrict__ qh, const ushort* __restrict__ ql,
    const ushort* __restrict__ kh, const ushort* __restrict__ kl,
    const ushort* __restrict__ vt, float* __restrict__ ctx) {
  const int h = blockIdx.y;
  const int s0 = blockIdx.x << 6;
  const int t = threadIdx.x;
  const int w = t >> 6, l = t & 63, lq = l & 15, g = l >> 4;

  __shared__ __align__(16) ushort Kh[4096];   // [64 kcol][64 d], 16B-chunk XOR swizzle
  __shared__ __align__(16) ushort Kl[4096];
  __shared__ __align__(16) ushort Vs[4096];   // [64 d][64 kcol] (vt tile)
  __shared__ __align__(16) ushort Pb[4][1024];// wave-private P [16 q][64 k]

  // Q A-fragments: lane holds Q[lq][g*8+i (+32)]
  s16x8 qa00, qa01, qa10, qa11;
  {
    const size_t qoff = ((size_t)h * S_LEN + s0 + (w << 4) + lq) * 64 + (g << 3);
    qa00 = *(const s16x8*)(qh + qoff);
    qa01 = *(const s16x8*)(qh + qoff + 32);
    qa10 = *(const s16x8*)(ql + qoff);
    qa11 = *(const s16x8*)(ql + qoff + 32);
  }

  f32x4 o[4];
#pragma unroll
  for (int n = 0; n < 4; ++n) o[n] = (f32x4){0.f, 0.f, 0.f, 0.f};
  float mrun[4] = {-3.0e30f, -3.0e30f, -3.0e30f, -3.0e30f};
  float lrun[4] = {0.f, 0.f, 0.f, 0.f};

  // staging: thread stages row r, chunks c0,c0+1 (8 bf16 each) of 3 buffers
  const int r = t >> 2, c0 = (t & 3) << 1;
  const ushort* gkh = kh + ((size_t)h * S_LEN + r) * 64 + (c0 << 3);
  const ushort* gkl = kl + ((size_t)h * S_LEN + r) * 64 + (c0 << 3);
  const ushort* gvt = vt + ((size_t)h * 64 + r) * S_LEN + (c0 << 3);
  const int lw0 = (r << 6) | ((c0 ^ (r & 7)) << 3);
  const int lw1 = (r << 6) | (((c0 + 1) ^ (r & 7)) << 3);

  // preload tile 0
  float4 skh0 = *(const float4*)(gkh);
  float4 skh1 = *(const float4*)(gkh + 8);
  float4 skl0 = *(const float4*)(gkl);
  float4 skl1 = *(const float4*)(gkl + 8);
  float4 svt0 = *(const float4*)(gvt);
  float4 svt1 = *(const float4*)(gvt + 8);

  for (int kt = 0; kt < 64; ++kt) {
    __syncthreads();
    *(float4*)&Kh[lw0] = skh0; *(float4*)&Kh[lw1] = skh1;
    *(float4*)&Kl[lw0] = skl0; *(float4*)&Kl[lw1] = skl1;
    *(float4*)&Vs[lw0] = svt0; *(float4*)&Vs[lw1] = svt1;
    __syncthreads();

    if (kt + 1 < 64) {   // issue next tile's loads; latency hides under compute
      const size_t go = (size_t)(kt + 1) * 64 * 64;
      const size_t gv = (size_t)(kt + 1) * 64;
      skh0 = *(const float4*)(gkh + go); skh1 = *(const float4*)(gkh + go + 8);
      skl0 = *(const float4*)(gkl + go); skl1 = *(const float4*)(gkl + go + 8);
      svt0 = *(const float4*)(gvt + gv); svt1 = *(const float4*)(gvt + gv + 8);
    }

    // ---- QK^T: S[16 q][64 k], split 3-term ----
    f32x4 sc[4];
#pragma unroll
    for (int n = 0; n < 4; ++n) {
      const int row = lq + (n << 4);
      const int sz0 = (row << 6) | (((g + 0) ^ (row & 7)) << 3);
      const int sz1 = (row << 6) | (((g + 4) ^ (row & 7)) << 3);
      const s16x8 bh0 = *(const s16x8*)&Kh[sz0];
      const s16x8 bh1 = *(const s16x8*)&Kh[sz1];
      const s16x8 bl0 = *(const s16x8*)&Kl[sz0];
      const s16x8 bl1 = *(const s16x8*)&Kl[sz1];
      f32x4 a = {0.f, 0.f, 0.f, 0.f};
      a = __builtin_amdgcn_mfma_f32_16x16x32_bf16(qa00, bh0, a, 0, 0, 0);
      a = __builtin_amdgcn_mfma_f32_16x16x32_bf16(qa01, bh1, a, 0, 0, 0);
      a = __builtin_amdgcn_mfma_f32_16x16x32_bf16(qa00, bl0, a, 0, 0, 0);
      a = __builtin_amdgcn_mfma_f32_16x16x32_bf16(qa01, bl1, a, 0, 0, 0);
      a = __builtin_amdgcn_mfma_f32_16x16x32_bf16(qa10, bh0, a, 0, 0, 0);
      a = __builtin_amdgcn_mfma_f32_16x16x32_bf16(qa11, bh1, a, 0, 0, 0);
      sc[n] = a;
    }

    // ---- online softmax (rows r=4g+reg live in the 16-lane group g) ----
    float pm[4];
#pragma unroll
    for (int rg = 0; rg < 4; ++rg)
      pm[rg] = fmaxf(fmaxf(sc[0][rg], sc[1][rg]), fmaxf(sc[2][rg], sc[3][rg]));
#pragma unroll
    for (int mask = 1; mask < 16; mask <<= 1)
#pragma unroll
      for (int rg = 0; rg < 4; ++rg)
        pm[rg] = fmaxf(pm[rg], __shfl_xor(pm[rg], mask, 64));

    float corr[4], pr[4][4], rs[4];
#pragma unroll
    for (int rg = 0; rg < 4; ++rg) {
      const float mn = fmaxf(mrun[rg], pm[rg]);
      corr[rg] = exp2f(mrun[rg] - mn);
      mrun[rg] = mn;
      float s = 0.f;
#pragma unroll
      for (int n = 0; n < 4; ++n) { pr[n][rg] = exp2f(sc[n][rg] - mn); s += pr[n][rg]; }
      rs[rg] = s;
    }
#pragma unroll
    for (int mask = 1; mask < 16; mask <<= 1)
#pragma unroll
      for (int rg = 0; rg < 4; ++rg) rs[rg] += __shfl_xor(rs[rg], mask, 64);
#pragma unroll
    for (int rg = 0; rg < 4; ++rg) lrun[rg] = lrun[rg] * corr[rg] + rs[rg];
#pragma unroll
    for (int n = 0; n < 4; ++n)
#pragma unroll
      for (int rg = 0; rg < 4; ++rg) o[n][rg] *= corr[rg];

    // ---- P -> wave-private LDS (bf16), read back as A-fragments ----
    ushort* Pw = Pb[w];
#pragma unroll
    for (int n = 0; n < 4; ++n)
#pragma unroll
      for (int rg = 0; rg < 4; ++rg) {
        const int prow = (g << 2) + rg;
        const int pcol = lq + (n << 4);
        Pw[(prow << 6) | ((((pcol >> 3) ^ (prow & 7)) << 3) | (pcol & 7))] =
            f2bf(pr[n][rg]);
      }
    const s16x8 pa0 = *(const s16x8*)&Pw[(lq << 6) | (((g + 0) ^ (lq & 7)) << 3)];
    const s16x8 pa1 = *(const s16x8*)&Pw[(lq << 6) | (((g + 4) ^ (lq & 7)) << 3)];

    // ---- PV: ctx[16 q][64 d] += P · V ----
#pragma unroll
    for (int n = 0; n < 4; ++n) {
      const int row = lq + (n << 4);
      const s16x8 v0 = *(const s16x8*)&Vs[(row << 6) | (((g + 0) ^ (row & 7)) << 3)];
      const s16x8 v1 = *(const s16x8*)&Vs[(row << 6) | (((g + 4) ^ (row & 7)) << 3)];
      o[n] = __builtin_amdgcn_mfma_f32_16x16x32_bf16(pa0, v0, o[n], 0, 0, 0);
      o[n] = __builtin_amdgcn_mfma_f32_16x16x32_bf16(pa1, v1, o[n], 0, 0, 0);
    }
  }

  // epilogue: divide by l, store ctx f32 [S][768]
  float inv[4];
#pragma unroll
  for (int rg = 0; rg < 4; ++rg) inv[rg] = 1.0f / lrun[rg];
#pragma unroll
  for (int n = 0; n < 4; ++n)
#pragma unroll
    for (int rg = 0; rg < 4; ++rg) {
      const int s = s0 + (w << 4) + (g << 2) + rg;
      ctx[(size_t)s * DMODEL + (h << 6) + lq + (n << 4)] = o[n][rg] * inv[rg];
    }
}

// ---------------- output projection GEMM 128x128x8 + bias ----------------
__global__ __launch_bounds__(256) void k_gemm_out(
    const float* __restrict__ Xc, const float* __restrict__ W,
    const float* __restrict__ bias, float* __restrict__ out) {
  __shared__ float As[8][132];
  __shared__ float Bs[8][132];
  const int t = threadIdx.x;
  const int m0 = blockIdx.y * 128;
  const int n0 = blockIdx.x * 128;
  const int ty = t >> 4, tx = t & 15;
  float acc[8][8];
#pragma unroll
  for (int i = 0; i < 8; ++i)
#pragma unroll
    for (int j = 0; j < 8; ++j) acc[i][j] = 0.f;

  const int ar = t >> 1, ak = (t & 1) << 2;
  const int br = t >> 5, bc = (t & 31) << 2;

  for (int k0 = 0; k0 < DMODEL; k0 += 8) {
    const float4 a4 = *(const float4*)(Xc + (size_t)(m0 + ar) * DMODEL + k0 + ak);
    const float4 b4 = *(const float4*)(W + (size_t)(k0 + br) * DMODEL + n0 + bc);
    __syncthreads();
    As[ak + 0][ar] = a4.x; As[ak + 1][ar] = a4.y;
    As[ak + 2][ar] = a4.z; As[ak + 3][ar] = a4.w;
    *(float4*)&Bs[br][bc] = b4;
    __syncthreads();
#pragma unroll
    for (int kk = 0; kk < 8; ++kk) {
      const float4 a0 = *(const float4*)&As[kk][ty * 8];
      const float4 a1 = *(const float4*)&As[kk][ty * 8 + 4];
      const float4 b0 = *(const float4*)&Bs[kk][tx * 8];
      const float4 b1 = *(const float4*)&Bs[kk][tx * 8 + 4];
      const float av[8] = {a0.x, a0.y, a0.z, a0.w, a1.x, a1.y, a1.z, a1.w};
      const float bv[8] = {b0.x, b0.y, b0.z, b0.w, b1.x, b1.y, b1.z, b1.w};
#pragma unroll
      for (int i = 0; i < 8; ++i)
#pragma unroll
        for (int j = 0; j < 8; ++j) acc[i][j] += av[i] * bv[j];
    }
  }
#pragma unroll
  for (int i = 0; i < 8; ++i) {
    const int s = m0 + ty * 8 + i;
    const int n = n0 + tx * 8;
    float4 r0, r1;
    r0.x = acc[i][0] + bias[n + 0]; r0.y = acc[i][1] + bias[n + 1];
    r0.z = acc[i][2] + bias[n + 2]; r0.w = acc[i][3] + bias[n + 3];
    r1.x = acc[i][4] + bias[n + 4]; r1.y = acc[i][5] + bias[n + 5];
    r1.z = acc[i][6] + bias[n + 6]; r1.w = acc[i][7] + bias[n + 7];
    *(float4*)(out + (size_t)s * DMODEL + n) = r0;
    *(float4*)(out + (size_t)s * DMODEL + n + 4) = r1;
  }
}

extern "C" void kernel_launch(void* const* d_in, const int* in_sizes, int n_in,
                              void* d_out, int out_size, void* d_ws, size_t ws_size,
                              hipStream_t stream) {
  const float* x    = (const float*)d_in[0];
  const float* Wqkv = (const float*)d_in[1];
  const float* bqkv = (const float*)d_in[2];
  const float* Wout = (const float*)d_in[3];
  const float* bout = (const float*)d_in[4];
  float* out = (float*)d_out;

  const size_t NQ = (size_t)NH * S_LEN * HD;   // 3,145,728 elements
  char* base = (char*)d_ws;
  ushort* qh = (ushort*)base;
  ushort* ql = qh + NQ;
  ushort* kh = ql + NQ;
  ushort* kl = kh + NQ;
  ushort* vt = kl + NQ;
  float* cx = (float*)(base + 5 * NQ * sizeof(ushort));
  float* ct = cx + (size_t)S_LEN * DMODEL;
  float* st = ct + (size_t)S_LEN * HD;

  k_build_trig<<<dim3(S_LEN), dim3(64), 0, stream>>>(ct, st);
  k_gemm_qkv<<<dim3((3 * DMODEL) / 128, S_LEN / 128), dim3(256), 0, stream>>>(
      x, Wqkv, bqkv, ct, st, qh, ql, kh, kl, vt);
  k_attn_mfma<<<dim3(S_LEN / 64, NH), dim3(256), 0, stream>>>(qh, ql, kh, kl, vt, cx);
  k_gemm_out<<<dim3(DMODEL / 128, S_LEN / 128), dim3(256), 0, stream>>>(
      cx, Wout, bout, out);
}

// Round 3
// 394.228 us; speedup vs baseline: 6.0562x; 1.5454x over previous
//
#include <hip/hip_runtime.h>
#include <hip/hip_bf16.h>
#include <math.h>

#define S_LEN 4096
#define DMODEL 768
#define NH 12
#define HD 64
#define BK 32

using f32x4 = __attribute__((ext_vector_type(4))) float;
using s16x8 = __attribute__((ext_vector_type(8))) short;

__device__ inline ushort f2bf(float f) {
  union { float f; uint32_t u; } v; v.f = f;
  uint32_t r = v.u + 0x7fffu + ((v.u >> 16) & 1u);   // RTNE
  return (ushort)(r >> 16);
}
__device__ inline float bf2f(ushort u) {
  union { uint32_t u; float f; } v; v.u = ((uint32_t)u) << 16;
  return v.f;
}

// scale folded into q: 1/sqrt(64) * log2(e)  -> softmax uses exp2
#define QSCL 0.18033688011112042f

// ---------------- RoPE trig table (double precision on device) ----------------
__global__ void k_build_trig(float* __restrict__ ct, float* __restrict__ st) {
  const int s = blockIdx.x;
  const int d = threadIdx.x;
  const int j = d & 31;
  const double inv = pow(10000.0, -(double)j / 32.0);
  const double a = (double)s * inv;
  ct[s * HD + d] = (float)cos(a);
  st[s * HD + d] = (float)sin(a);
}

// ---------------- transpose + hi/lo bf16 split: W[R][C] -> T[C][R] ----------
__global__ __launch_bounds__(256) void k_tsplit(
    const float* __restrict__ W, ushort* __restrict__ Th,
    ushort* __restrict__ Tl, int R, int C) {
  __shared__ float tile[32][33];
  const int tx = threadIdx.x & 31, ty = threadIdx.x >> 5;  // 32 x 8
  const int c0 = blockIdx.x * 32, r0 = blockIdx.y * 32;
#pragma unroll
  for (int i = 0; i < 4; ++i)
    tile[ty + 8 * i][tx] = W[(size_t)(r0 + ty + 8 * i) * C + c0 + tx];
  __syncthreads();
#pragma unroll
  for (int i = 0; i < 4; ++i) {
    const float v = tile[tx][ty + 8 * i];
    const ushort h = f2bf(v);
    const size_t off = (size_t)(c0 + ty + 8 * i) * R + r0 + tx;
    Th[off] = h;
    Tl[off] = f2bf(v - bf2f(h));
  }
}

// ---------------- split-bf16 MFMA GEMM, 128x128 tile, BK=32 ------------------
// A fp32 [M][768] (split in staging), B pre-split bf16 [N][768] (row = n).
// EPI 0: qkv epilogue (bias + RoPE + hi/lo scatter + V transpose)
// EPI 1: out epilogue (bias + fp32 store)
template <int EPI>
__global__ __launch_bounds__(256) void k_gemm_split(
    const float* __restrict__ A, const ushort* __restrict__ Bh,
    const ushort* __restrict__ Bl, const float* __restrict__ bias,
    const float* __restrict__ ct, const float* __restrict__ st,
    ushort* __restrict__ qh, ushort* __restrict__ ql,
    ushort* __restrict__ kh, ushort* __restrict__ kl,
    ushort* __restrict__ vt, float* __restrict__ out) {
  __shared__ __align__(16) ushort sAh[128 * BK];
  __shared__ __align__(16) ushort sAl[128 * BK];
  __shared__ __align__(16) ushort sBh[128 * BK];
  __shared__ __align__(16) ushort sBl[128 * BK];

  const int t = threadIdx.x;
  const int w = t >> 6, l = t & 63, g = l >> 4, lq = l & 15;
  const int wm = w >> 1, wn = w & 1;
  const int m0 = blockIdx.y * 128, n0 = blockIdx.x * 128;

  f32x4 acc[4][4];
#pragma unroll
  for (int i = 0; i < 4; ++i)
#pragma unroll
    for (int j = 0; j < 4; ++j) acc[i][j] = (f32x4){0.f, 0.f, 0.f, 0.f};

  // staging: thread covers row ra, k-halfseg ks (16 k each), both A and B
  const int ra = t >> 1, ks = (t & 1) << 4;
  const float* Asrc = A + (size_t)(m0 + ra) * 768 + ks;
  const ushort* Bhsrc = Bh + (size_t)(n0 + ra) * 768 + ks;
  const ushort* Blsrc = Bl + (size_t)(n0 + ra) * 768 + ks;
  // LDS write slots (shorts), chunk-XOR swizzle: chunk ^= row&3
  const int c0 = (t & 1) << 1;
  const int wo0 = ra * BK + (((c0 + 0) ^ (ra & 3)) << 3);
  const int wo1 = ra * BK + (((c0 + 1) ^ (ra & 3)) << 3);

  float4 a0 = *(const float4*)(Asrc + 0);
  float4 a1 = *(const float4*)(Asrc + 4);
  float4 a2 = *(const float4*)(Asrc + 8);
  float4 a3 = *(const float4*)(Asrc + 12);
  float4 bh0 = *(const float4*)(Bhsrc);
  float4 bh1 = *(const float4*)(Bhsrc + 8);
  float4 bl0 = *(const float4*)(Blsrc);
  float4 bl1 = *(const float4*)(Blsrc + 8);

  for (int kt = 0; kt < 768 / BK; ++kt) {
    __syncthreads();
    {  // split A 16 floats -> hi/lo shorts, write LDS
      const float af[16] = {a0.x, a0.y, a0.z, a0.w, a1.x, a1.y, a1.z, a1.w,
                            a2.x, a2.y, a2.z, a2.w, a3.x, a3.y, a3.z, a3.w};
      union { ushort us[8]; float4 f4; } h0, h1, l0v, l1v;
#pragma unroll
      for (int i = 0; i < 8; ++i) {
        const ushort h = f2bf(af[i]);
        h0.us[i] = h; l0v.us[i] = f2bf(af[i] - bf2f(h));
      }
#pragma unroll
      for (int i = 0; i < 8; ++i) {
        const ushort h = f2bf(af[8 + i]);
        h1.us[i] = h; l1v.us[i] = f2bf(af[8 + i] - bf2f(h));
      }
      *(float4*)&sAh[wo0] = h0.f4; *(float4*)&sAh[wo1] = h1.f4;
      *(float4*)&sAl[wo0] = l0v.f4; *(float4*)&sAl[wo1] = l1v.f4;
      *(float4*)&sBh[wo0] = bh0; *(float4*)&sBh[wo1] = bh1;
      *(float4*)&sBl[wo0] = bl0; *(float4*)&sBl[wo1] = bl1;
    }
    __syncthreads();
    if (kt + 1 < 768 / BK) {
      const int ko = (kt + 1) * BK;
      a0 = *(const float4*)(Asrc + ko + 0);
      a1 = *(const float4*)(Asrc + ko + 4);
      a2 = *(const float4*)(Asrc + ko + 8);
      a3 = *(const float4*)(Asrc + ko + 12);
      bh0 = *(const float4*)(Bhsrc + ko);
      bh1 = *(const float4*)(Bhsrc + ko + 8);
      bl0 = *(const float4*)(Blsrc + ko);
      bl1 = *(const float4*)(Blsrc + ko + 8);
    }
    // fragments + MFMA
    s16x8 ah[4], al[4];
#pragma unroll
    for (int mf = 0; mf < 4; ++mf) {
      const int arow = wm * 64 + mf * 16 + lq;
      const int off = arow * BK + ((g ^ (arow & 3)) << 3);
      ah[mf] = *(const s16x8*)&sAh[off];
      al[mf] = *(const s16x8*)&sAl[off];
    }
#pragma unroll
    for (int nf = 0; nf < 4; ++nf) {
      const int brow = wn * 64 + nf * 16 + lq;
      const int off = brow * BK + ((g ^ (brow & 3)) << 3);
      const s16x8 bhf = *(const s16x8*)&sBh[off];
      const s16x8 blf = *(const s16x8*)&sBl[off];
#pragma unroll
      for (int mf = 0; mf < 4; ++mf) {
        acc[mf][nf] = __builtin_amdgcn_mfma_f32_16x16x32_bf16(ah[mf], bhf, acc[mf][nf], 0, 0, 0);
        acc[mf][nf] = __builtin_amdgcn_mfma_f32_16x16x32_bf16(ah[mf], blf, acc[mf][nf], 0, 0, 0);
        acc[mf][nf] = __builtin_amdgcn_mfma_f32_16x16x32_bf16(al[mf], bhf, acc[mf][nf], 0, 0, 0);
      }
    }
  }

  // ---- epilogue: lane (g,lq) holds D[m = wm*64+mf*16+g*4+rg][n = wn*64+nf*16+lq]
  if (EPI == 0) {
    const int cidx = n0 / DMODEL;   // 0:q 1:k 2:v (block-uniform)
    if (cidx < 2) {
      ushort* dh = (cidx == 0) ? qh : kh;
      ushort* dl = (cidx == 0) ? ql : kl;
      const float scl = (cidx == 0) ? QSCL : 1.0f;
#pragma unroll
      for (int nf = 0; nf < 4; ++nf) {
        const int n = n0 + wn * 64 + nf * 16 + lq;
        const int rem = n - cidx * DMODEL;
        const int hh = rem >> 6, d = rem & 63;
        const float sgn = (d & 1) ? 1.f : -1.f;
        const float bb = bias[n];
#pragma unroll
        for (int mf = 0; mf < 4; ++mf)
#pragma unroll
          for (int rg = 0; rg < 4; ++rg) {
            const int s = m0 + wm * 64 + mf * 16 + g * 4 + rg;
            const float v = acc[mf][nf][rg] + bb;
            const float vp = __shfl_xor(v, 1, 64);
            const float o = (v * ct[s * HD + d] + sgn * vp * st[s * HD + d]) * scl;
            const ushort hv = f2bf(o);
            const size_t off = (((size_t)hh * S_LEN + s) << 6) + d;
            dh[off] = hv;
            dl[off] = f2bf(o - bf2f(hv));
          }
      }
    } else {
#pragma unroll
      for (int nf = 0; nf < 4; ++nf) {
        const int n = n0 + wn * 64 + nf * 16 + lq;
        const int rem = n - 2 * DMODEL;
        const int hh = rem >> 6, d = rem & 63;
        const float bb = bias[n];
#pragma unroll
        for (int mf = 0; mf < 4; ++mf) {
          union { ushort us[4]; ushort4 u4; } u;
#pragma unroll
          for (int rg = 0; rg < 4; ++rg) u.us[rg] = f2bf(acc[mf][nf][rg] + bb);
          const int sb = m0 + wm * 64 + mf * 16 + g * 4;
          *(ushort4*)(vt + ((size_t)hh * 64 + d) * S_LEN + sb) = u.u4;
        }
      }
    }
  } else {
#pragma unroll
    for (int nf = 0; nf < 4; ++nf) {
      const int n = n0 + wn * 64 + nf * 16 + lq;
      const float bb = bias[n];
#pragma unroll
      for (int mf = 0; mf < 4; ++mf)
#pragma unroll
        for (int rg = 0; rg < 4; ++rg) {
          const int s = m0 + wm * 64 + mf * 16 + g * 4 + rg;
          out[(size_t)s * DMODEL + n] = acc[mf][nf][rg] + bb;
        }
    }
  }
}

// ---------------- flash attention, split-bf16 MFMA (unchanged) ---------------
__global__ __launch_bounds__(256) void k_attn_mfma(
    const ushort* __restrict__ qh, const ushort* __restrict__ ql,
    const ushort* __restrict__ kh, const ushort* __restrict__ kl,
    const ushort* __restrict__ vt, float* __restrict__ ctx) {
  const int h = blockIdx.y;
  const int s0 = blockIdx.x << 6;
  const int t = threadIdx.x;
  const int w = t >> 6, l = t & 63, lq = l & 15, g = l >> 4;

  __shared__ __align__(16) ushort Kh[4096];
  __shared__ __align__(16) ushort Kl[4096];
  __shared__ __align__(16) ushort Vs[4096];
  __shared__ __align__(16) ushort Pb[4][1024];

  s16x8 qa00, qa01, qa10, qa11;
  {
    const size_t qoff = ((size_t)h * S_LEN + s0 + (w << 4) + lq) * 64 + (g << 3);
    qa00 = *(const s16x8*)(qh + qoff);
    qa01 = *(const s16x8*)(qh + qoff + 32);
    qa10 = *(const s16x8*)(ql + qoff);
    qa11 = *(const s16x8*)(ql + qoff + 32);
  }

  f32x4 o[4];
#pragma unroll
  for (int n = 0; n < 4; ++n) o[n] = (f32x4){0.f, 0.f, 0.f, 0.f};
  float mrun[4] = {-3.0e30f, -3.0e30f, -3.0e30f, -3.0e30f};
  float lrun[4] = {0.f, 0.f, 0.f, 0.f};

  const int r = t >> 2, c0 = (t & 3) << 1;
  const ushort* gkh = kh + ((size_t)h * S_LEN + r) * 64 + (c0 << 3);
  const ushort* gkl = kl + ((size_t)h * S_LEN + r) * 64 + (c0 << 3);
  const ushort* gvt = vt + ((size_t)h * 64 + r) * S_LEN + (c0 << 3);
  const int lw0 = (r << 6) | ((c0 ^ (r & 7)) << 3);
  const int lw1 = (r << 6) | (((c0 + 1) ^ (r & 7)) << 3);

  float4 skh0 = *(const float4*)(gkh);
  float4 skh1 = *(const float4*)(gkh + 8);
  float4 skl0 = *(const float4*)(gkl);
  float4 skl1 = *(const float4*)(gkl + 8);
  float4 svt0 = *(const float4*)(gvt);
  float4 svt1 = *(const float4*)(gvt + 8);

  for (int kt = 0; kt < 64; ++kt) {
    __syncthreads();
    *(float4*)&Kh[lw0] = skh0; *(float4*)&Kh[lw1] = skh1;
    *(float4*)&Kl[lw0] = skl0; *(float4*)&Kl[lw1] = skl1;
    *(float4*)&Vs[lw0] = svt0; *(float4*)&Vs[lw1] = svt1;
    __syncthreads();

    if (kt + 1 < 64) {
      const size_t go = (size_t)(kt + 1) * 64 * 64;
      const size_t gv = (size_t)(kt + 1) * 64;
      skh0 = *(const float4*)(gkh + go); skh1 = *(const float4*)(gkh + go + 8);
      skl0 = *(const float4*)(gkl + go); skl1 = *(const float4*)(gkl + go + 8);
      svt0 = *(const float4*)(gvt + gv); svt1 = *(const float4*)(gvt + gv + 8);
    }

    f32x4 sc[4];
#pragma unroll
    for (int n = 0; n < 4; ++n) {
      const int row = lq + (n << 4);
      const int sz0 = (row << 6) | (((g + 0) ^ (row & 7)) << 3);
      const int sz1 = (row << 6) | (((g + 4) ^ (row & 7)) << 3);
      const s16x8 bh0 = *(const s16x8*)&Kh[sz0];
      const s16x8 bh1 = *(const s16x8*)&Kh[sz1];
      const s16x8 bl0 = *(const s16x8*)&Kl[sz0];
      const s16x8 bl1 = *(const s16x8*)&Kl[sz1];
      f32x4 a = {0.f, 0.f, 0.f, 0.f};
      a = __builtin_amdgcn_mfma_f32_16x16x32_bf16(qa00, bh0, a, 0, 0, 0);
      a = __builtin_amdgcn_mfma_f32_16x16x32_bf16(qa01, bh1, a, 0, 0, 0);
      a = __builtin_amdgcn_mfma_f32_16x16x32_bf16(qa00, bl0, a, 0, 0, 0);
      a = __builtin_amdgcn_mfma_f32_16x16x32_bf16(qa01, bl1, a, 0, 0, 0);
      a = __builtin_amdgcn_mfma_f32_16x16x32_bf16(qa10, bh0, a, 0, 0, 0);
      a = __builtin_amdgcn_mfma_f32_16x16x32_bf16(qa11, bh1, a, 0, 0, 0);
      sc[n] = a;
    }

    float pm[4];
#pragma unroll
    for (int rg = 0; rg < 4; ++rg)
      pm[rg] = fmaxf(fmaxf(sc[0][rg], sc[1][rg]), fmaxf(sc[2][rg], sc[3][rg]));
#pragma unroll
    for (int mask = 1; mask < 16; mask <<= 1)
#pragma unroll
      for (int rg = 0; rg < 4; ++rg)
        pm[rg] = fmaxf(pm[rg], __shfl_xor(pm[rg], mask, 64));

    float corr[4], pr[4][4], rs[4];
#pragma unroll
    for (int rg = 0; rg < 4; ++rg) {
      const float mn = fmaxf(mrun[rg], pm[rg]);
      corr[rg] = exp2f(mrun[rg] - mn);
      mrun[rg] = mn;
      float s = 0.f;
#pragma unroll
      for (int n = 0; n < 4; ++n) { pr[n][rg] = exp2f(sc[n][rg] - mn); s += pr[n][rg]; }
      rs[rg] = s;
    }
#pragma unroll
    for (int mask = 1; mask < 16; mask <<= 1)
#pragma unroll
      for (int rg = 0; rg < 4; ++rg) rs[rg] += __shfl_xor(rs[rg], mask, 64);
#pragma unroll
    for (int rg = 0; rg < 4; ++rg) lrun[rg] = lrun[rg] * corr[rg] + rs[rg];
#pragma unroll
    for (int n = 0; n < 4; ++n)
#pragma unroll
      for (int rg = 0; rg < 4; ++rg) o[n][rg] *= corr[rg];

    ushort* Pw = Pb[w];
#pragma unroll
    for (int n = 0; n < 4; ++n)
#pragma unroll
      for (int rg = 0; rg < 4; ++rg) {
        const int prow = (g << 2) + rg;
        const int pcol = lq + (n << 4);
        Pw[(prow << 6) | ((((pcol >> 3) ^ (prow & 7)) << 3) | (pcol & 7))] =
            f2bf(pr[n][rg]);
      }
    const s16x8 pa0 = *(const s16x8*)&Pw[(lq << 6) | (((g + 0) ^ (lq & 7)) << 3)];
    const s16x8 pa1 = *(const s16x8*)&Pw[(lq << 6) | (((g + 4) ^ (lq & 7)) << 3)];

#pragma unroll
    for (int n = 0; n < 4; ++n) {
      const int row = lq + (n << 4);
      const s16x8 v0 = *(const s16x8*)&Vs[(row << 6) | (((g + 0) ^ (row & 7)) << 3)];
      const s16x8 v1 = *(const s16x8*)&Vs[(row << 6) | (((g + 4) ^ (row & 7)) << 3)];
      o[n] = __builtin_amdgcn_mfma_f32_16x16x32_bf16(pa0, v0, o[n], 0, 0, 0);
      o[n] = __builtin_amdgcn_mfma_f32_16x16x32_bf16(pa1, v1, o[n], 0, 0, 0);
    }
  }

  float inv[4];
#pragma unroll
  for (int rg = 0; rg < 4; ++rg) inv[rg] = 1.0f / lrun[rg];
#pragma unroll
  for (int n = 0; n < 4; ++n)
#pragma unroll
    for (int rg = 0; rg < 4; ++rg) {
      const int s = s0 + (w << 4) + (g << 2) + rg;
      ctx[(size_t)s * DMODEL + (h << 6) + lq + (n << 4)] = o[n][rg] * inv[rg];
    }
}

extern "C" void kernel_launch(void* const* d_in, const int* in_sizes, int n_in,
                              void* d_out, int out_size, void* d_ws, size_t ws_size,
                              hipStream_t stream) {
  const float* x    = (const float*)d_in[0];
  const float* Wqkv = (const float*)d_in[1];
  const float* bqkv = (const float*)d_in[2];
  const float* Wout = (const float*)d_in[3];
  const float* bout = (const float*)d_in[4];
  float* out = (float*)d_out;

  const size_t NQ = (size_t)NH * S_LEN * HD;   // 3,145,728
  char* base = (char*)d_ws;
  ushort* qh = (ushort*)base;
  ushort* ql = qh + NQ;
  ushort* kh = ql + NQ;
  ushort* kl = kh + NQ;
  ushort* vt = kl + NQ;
  float* cx = (float*)(vt + NQ);                       // [S][D] fp32
  float* ct = cx + (size_t)S_LEN * DMODEL;
  float* st = ct + (size_t)S_LEN * HD;
  ushort* Wth = (ushort*)(st + (size_t)S_LEN * HD);    // [2304][768]
  ushort* Wtl = Wth + (size_t)3 * DMODEL * DMODEL;
  ushort* Woth = Wtl + (size_t)3 * DMODEL * DMODEL;    // [768][768]
  ushort* Wotl = Woth + (size_t)DMODEL * DMODEL;

  k_build_trig<<<dim3(S_LEN), dim3(64), 0, stream>>>(ct, st);
  k_tsplit<<<dim3(3 * DMODEL / 32, DMODEL / 32), dim3(256), 0, stream>>>(
      Wqkv, Wth, Wtl, DMODEL, 3 * DMODEL);
  k_tsplit<<<dim3(DMODEL / 32, DMODEL / 32), dim3(256), 0, stream>>>(
      Wout, Woth, Wotl, DMODEL, DMODEL);
  k_gemm_split<0><<<dim3(3 * DMODEL / 128, S_LEN / 128), dim3(256), 0, stream>>>(
      x, Wth, Wtl, bqkv, ct, st, qh, ql, kh, kl, vt, nullptr);
  k_attn_mfma<<<dim3(S_LEN / 64, NH), dim3(256), 0, stream>>>(qh, ql, kh, kl, vt, cx);
  k_gemm_split<1><<<dim3(DMODEL / 128, S_LEN / 128), dim3(256), 0, stream>>>(
      cx, Woth, Wotl, bout, nullptr, nullptr,
      nullptr, nullptr, nullptr, nullptr, nullptr, out);
}

// Round 4
// 270.240 us; speedup vs baseline: 8.8348x; 1.4588x over previous
//
#include <hip/hip_runtime.h>
#include <hip/hip_bf16.h>
#include <math.h>

#define S_LEN 4096
#define DMODEL 768
#define NH 12
#define HD 64
#define BK 32

using f32x4 = __attribute__((ext_vector_type(4))) float;
using s16x8 = __attribute__((ext_vector_type(8))) short;

__device__ inline ushort f2bf(float f) {
  union { float f; uint32_t u; } v; v.f = f;
  uint32_t r = v.u + 0x7fffu + ((v.u >> 16) & 1u);   // RTNE
  return (ushort)(r >> 16);
}
__device__ inline float bf2f(ushort u) {
  union { uint32_t u; float f; } v; v.u = ((uint32_t)u) << 16;
  return v.f;
}

// scale folded into q: 1/sqrt(64) * log2(e)  -> softmax uses exp2
#define QSCL 0.18033688011112042f

// ---------------- RoPE trig table (double precision on device) ----------------
__global__ void k_build_trig(float* __restrict__ ct, float* __restrict__ st) {
  const int s = blockIdx.x;
  const int d = threadIdx.x;
  const int j = d & 31;
  const double inv = pow(10000.0, -(double)j / 32.0);
  const double a = (double)s * inv;
  ct[s * HD + d] = (float)cos(a);
  st[s * HD + d] = (float)sin(a);
}

// ---------------- transpose + hi/lo bf16 split: W[R][C] -> T[C][R] ----------
__global__ __launch_bounds__(256) void k_tsplit(
    const float* __restrict__ W, ushort* __restrict__ Th,
    ushort* __restrict__ Tl, int R, int C) {
  __shared__ float tile[32][33];
  const int tx = threadIdx.x & 31, ty = threadIdx.x >> 5;  // 32 x 8
  const int c0 = blockIdx.x * 32, r0 = blockIdx.y * 32;
#pragma unroll
  for (int i = 0; i < 4; ++i)
    tile[ty + 8 * i][tx] = W[(size_t)(r0 + ty + 8 * i) * C + c0 + tx];
  __syncthreads();
#pragma unroll
  for (int i = 0; i < 4; ++i) {
    const float v = tile[tx][ty + 8 * i];
    const ushort h = f2bf(v);
    const size_t off = (size_t)(c0 + ty + 8 * i) * R + r0 + tx;
    Th[off] = h;
    Tl[off] = f2bf(v - bf2f(h));
  }
}

// ---------------- split-bf16 MFMA GEMM, 128x128 tile, BK=32 ------------------
// EPI 0: qkv epilogue (bias + RoPE; q -> hi/lo, k -> hi only, V transposed)
// EPI 1: out epilogue (bias + fp32 store)
template <int EPI>
__global__ __launch_bounds__(256) void k_gemm_split(
    const float* __restrict__ A, const ushort* __restrict__ Bh,
    const ushort* __restrict__ Bl, const float* __restrict__ bias,
    const float* __restrict__ ct, const float* __restrict__ st,
    ushort* __restrict__ qh, ushort* __restrict__ ql,
    ushort* __restrict__ kh, ushort* __restrict__ vt,
    float* __restrict__ out) {
  __shared__ __align__(16) ushort sAh[128 * BK];
  __shared__ __align__(16) ushort sAl[128 * BK];
  __shared__ __align__(16) ushort sBh[128 * BK];
  __shared__ __align__(16) ushort sBl[128 * BK];

  const int t = threadIdx.x;
  const int w = t >> 6, l = t & 63, g = l >> 4, lq = l & 15;
  const int wm = w >> 1, wn = w & 1;
  const int m0 = blockIdx.y * 128, n0 = blockIdx.x * 128;

  f32x4 acc[4][4];
#pragma unroll
  for (int i = 0; i < 4; ++i)
#pragma unroll
    for (int j = 0; j < 4; ++j) acc[i][j] = (f32x4){0.f, 0.f, 0.f, 0.f};

  const int ra = t >> 1, ks = (t & 1) << 4;
  const float* Asrc = A + (size_t)(m0 + ra) * 768 + ks;
  const ushort* Bhsrc = Bh + (size_t)(n0 + ra) * 768 + ks;
  const ushort* Blsrc = Bl + (size_t)(n0 + ra) * 768 + ks;
  const int c0 = (t & 1) << 1;
  const int wo0 = ra * BK + (((c0 + 0) ^ (ra & 3)) << 3);
  const int wo1 = ra * BK + (((c0 + 1) ^ (ra & 3)) << 3);

  float4 a0 = *(const float4*)(Asrc + 0);
  float4 a1 = *(const float4*)(Asrc + 4);
  float4 a2 = *(const float4*)(Asrc + 8);
  float4 a3 = *(const float4*)(Asrc + 12);
  float4 bh0 = *(const float4*)(Bhsrc);
  float4 bh1 = *(const float4*)(Bhsrc + 8);
  float4 bl0 = *(const float4*)(Blsrc);
  float4 bl1 = *(const float4*)(Blsrc + 8);

  for (int kt = 0; kt < 768 / BK; ++kt) {
    __syncthreads();
    {
      const float af[16] = {a0.x, a0.y, a0.z, a0.w, a1.x, a1.y, a1.z, a1.w,
                            a2.x, a2.y, a2.z, a2.w, a3.x, a3.y, a3.z, a3.w};
      union { ushort us[8]; float4 f4; } h0, h1, l0v, l1v;
#pragma unroll
      for (int i = 0; i < 8; ++i) {
        const ushort hh = f2bf(af[i]);
        h0.us[i] = hh; l0v.us[i] = f2bf(af[i] - bf2f(hh));
      }
#pragma unroll
      for (int i = 0; i < 8; ++i) {
        const ushort hh = f2bf(af[8 + i]);
        h1.us[i] = hh; l1v.us[i] = f2bf(af[8 + i] - bf2f(hh));
      }
      *(float4*)&sAh[wo0] = h0.f4; *(float4*)&sAh[wo1] = h1.f4;
      *(float4*)&sAl[wo0] = l0v.f4; *(float4*)&sAl[wo1] = l1v.f4;
      *(float4*)&sBh[wo0] = bh0; *(float4*)&sBh[wo1] = bh1;
      *(float4*)&sBl[wo0] = bl0; *(float4*)&sBl[wo1] = bl1;
    }
    __syncthreads();
    if (kt + 1 < 768 / BK) {
      const int ko = (kt + 1) * BK;
      a0 = *(const float4*)(Asrc + ko + 0);
      a1 = *(const float4*)(Asrc + ko + 4);
      a2 = *(const float4*)(Asrc + ko + 8);
      a3 = *(const float4*)(Asrc + ko + 12);
      bh0 = *(const float4*)(Bhsrc + ko);
      bh1 = *(const float4*)(Bhsrc + ko + 8);
      bl0 = *(const float4*)(Blsrc + ko);
      bl1 = *(const float4*)(Blsrc + ko + 8);
    }
    s16x8 ah[4], al[4];
#pragma unroll
    for (int mf = 0; mf < 4; ++mf) {
      const int arow = wm * 64 + mf * 16 + lq;
      const int off = arow * BK + ((g ^ (arow & 3)) << 3);
      ah[mf] = *(const s16x8*)&sAh[off];
      al[mf] = *(const s16x8*)&sAl[off];
    }
#pragma unroll
    for (int nf = 0; nf < 4; ++nf) {
      const int brow = wn * 64 + nf * 16 + lq;
      const int off = brow * BK + ((g ^ (brow & 3)) << 3);
      const s16x8 bhf = *(const s16x8*)&sBh[off];
      const s16x8 blf = *(const s16x8*)&sBl[off];
#pragma unroll
      for (int mf = 0; mf < 4; ++mf) {
        acc[mf][nf] = __builtin_amdgcn_mfma_f32_16x16x32_bf16(ah[mf], bhf, acc[mf][nf], 0, 0, 0);
        acc[mf][nf] = __builtin_amdgcn_mfma_f32_16x16x32_bf16(ah[mf], blf, acc[mf][nf], 0, 0, 0);
        acc[mf][nf] = __builtin_amdgcn_mfma_f32_16x16x32_bf16(al[mf], bhf, acc[mf][nf], 0, 0, 0);
      }
    }
  }

  if (EPI == 0) {
    const int cidx = n0 / DMODEL;   // 0:q 1:k 2:v (block-uniform)
    if (cidx < 2) {
      ushort* dh = (cidx == 0) ? qh : kh;
      const float scl = (cidx == 0) ? QSCL : 1.0f;
#pragma unroll
      for (int nf = 0; nf < 4; ++nf) {
        const int n = n0 + wn * 64 + nf * 16 + lq;
        const int rem = n - cidx * DMODEL;
        const int hh = rem >> 6, d = rem & 63;
        const float sgn = (d & 1) ? 1.f : -1.f;
        const float bb = bias[n];
#pragma unroll
        for (int mf = 0; mf < 4; ++mf)
#pragma unroll
          for (int rg = 0; rg < 4; ++rg) {
            const int s = m0 + wm * 64 + mf * 16 + g * 4 + rg;
            const float v = acc[mf][nf][rg] + bb;
            const float vp = __shfl_xor(v, 1, 64);
            const float o = (v * ct[s * HD + d] + sgn * vp * st[s * HD + d]) * scl;
            const ushort hv = f2bf(o);
            const size_t off = (((size_t)hh * S_LEN + s) << 6) + d;
            dh[off] = hv;
            if (cidx == 0) ql[off] = f2bf(o - bf2f(hv));
          }
      }
    } else {
#pragma unroll
      for (int nf = 0; nf < 4; ++nf) {
        const int n = n0 + wn * 64 + nf * 16 + lq;
        const int rem = n - 2 * DMODEL;
        const int hh = rem >> 6, d = rem & 63;
        const float bb = bias[n];
#pragma unroll
        for (int mf = 0; mf < 4; ++mf) {
          union { ushort us[4]; ushort4 u4; } u;
#pragma unroll
          for (int rg = 0; rg < 4; ++rg) u.us[rg] = f2bf(acc[mf][nf][rg] + bb);
          const int sb = m0 + wm * 64 + mf * 16 + g * 4;
          *(ushort4*)(vt + ((size_t)hh * 64 + d) * S_LEN + sb) = u.u4;
        }
      }
    }
  } else {
#pragma unroll
    for (int nf = 0; nf < 4; ++nf) {
      const int n = n0 + wn * 64 + nf * 16 + lq;
      const float bb = bias[n];
#pragma unroll
      for (int mf = 0; mf < 4; ++mf)
#pragma unroll
        for (int rg = 0; rg < 4; ++rg) {
          const int s = m0 + wm * 64 + mf * 16 + g * 4 + rg;
          out[(size_t)s * DMODEL + n] = acc[mf][nf][rg] + bb;
        }
    }
  }
}

// ---------------- flash attention: swapped QK^T, dbuf LDS, in-reg P ----------
// grid (S/64, H), 256 threads = 4 waves; wave w owns q-rows s0+16w..+15.
// S^T = mfma(K, Q): lane (g,lq) holds S^T[k=16n+4g+rg][q=lq].
// V k-columns permuted in LDS (pi: k_mfma=8g+i <-> real k=16(i>>2)+4g+(i&3))
// so natural P^T register layout IS the PV B-fragment (8 cvt_pk only).
__global__ __launch_bounds__(256) void k_attn_mfma(
    const ushort* __restrict__ qh, const ushort* __restrict__ ql,
    const ushort* __restrict__ kh, const ushort* __restrict__ vt,
    float* __restrict__ ctx) {
  const int h = blockIdx.y;
  const int s0 = blockIdx.x << 6;
  const int t = threadIdx.x;
  const int w = t >> 6, l = t & 63, lq = l & 15, g = l >> 4;

  __shared__ __align__(16) ushort Ks[2][4096];   // [64 k][64 d], chunk-XOR swz
  __shared__ __align__(16) ushort Vs[2][4096];   // [64 d][64 k-permuted], swz

  // Q B-fragments (hi+lo, two d-halves): lane holds Q[lq][8g..+7 (+32)]
  s16x8 qa00, qa01, qa10, qa11;
  {
    const size_t qoff = ((size_t)h * S_LEN + s0 + (w << 4) + lq) * 64 + (g << 3);
    qa00 = *(const s16x8*)(qh + qoff);
    qa01 = *(const s16x8*)(qh + qoff + 32);
    qa10 = *(const s16x8*)(ql + qoff);
    qa11 = *(const s16x8*)(ql + qoff + 32);
  }

  f32x4 o[4];
#pragma unroll
  for (int m = 0; m < 4; ++m) o[m] = (f32x4){0.f, 0.f, 0.f, 0.f};
  float mrun = -3.0e30f, lrun = 0.f;

  // staging: thread covers row r (0..63), real 8-col chunks c0, c0+1
  const int r = t >> 2, c0 = (t & 3) << 1;
  const ushort* gk = kh + ((size_t)h * S_LEN + r) * 64 + (c0 << 3);
  const ushort* gv = vt + ((size_t)h * 64 + r) * S_LEN + (c0 << 3);
  const int kw0 = (r << 6) | ((c0 ^ (r & 7)) << 3);
  const int kw1 = (r << 6) | (((c0 + 1) ^ (r & 7)) << 3);
  // V write offsets: real chunk c -> two 4-col runs in permuted space
  int vw[2][2];
#pragma unroll
  for (int cc = 0; cc < 2; ++cc) {
    const int c = c0 + cc;
    const int k5 = c >> 2, k4 = (c >> 1) & 1, k3 = c & 1;
#pragma unroll
    for (int hh = 0; hh < 2; ++hh) {
      const int ch = 4 * k5 + 2 * k3 + hh;      // permuted chunk
      vw[cc][hh] = (r << 6) | ((ch ^ (r & 7)) << 3) | (k4 << 2);
    }
  }

  float4 sk0 = *(const float4*)(gk);
  float4 sk1 = *(const float4*)(gk + 8);
  float4 sv0 = *(const float4*)(gv);
  float4 sv1 = *(const float4*)(gv + 8);

  {
    *(float4*)&Ks[0][kw0] = sk0;
    *(float4*)&Ks[0][kw1] = sk1;
    union { float4 f; ushort4 h4[2]; } va, vb;
    va.f = sv0; vb.f = sv1;
    *(ushort4*)&Vs[0][vw[0][0]] = va.h4[0];
    *(ushort4*)&Vs[0][vw[0][1]] = va.h4[1];
    *(ushort4*)&Vs[0][vw[1][0]] = vb.h4[0];
    *(ushort4*)&Vs[0][vw[1][1]] = vb.h4[1];
  }
  __syncthreads();

  for (int kt = 0; kt < 64; ++kt) {
    const int cur = kt & 1;
    if (kt + 1 < 64) {  // issue next tile's loads early (hide under compute)
      const size_t go = (size_t)(kt + 1) << 12;
      const size_t gvo = (size_t)(kt + 1) << 6;
      sk0 = *(const float4*)(gk + go);
      sk1 = *(const float4*)(gk + go + 8);
      sv0 = *(const float4*)(gv + gvo);
      sv1 = *(const float4*)(gv + gvo + 8);
    }

    // ---- QK^T swapped: sc[n][rg] = S^T[16n+4g+rg][lq] ----
    f32x4 sc[4];
#pragma unroll
    for (int n = 0; n < 4; ++n) {
      const int row = (n << 4) | lq;
      const int o0 = (row << 6) | (((g + 0) ^ (row & 7)) << 3);
      const int o1 = (row << 6) | (((g + 4) ^ (row & 7)) << 3);
      const s16x8 ka0 = *(const s16x8*)&Ks[cur][o0];
      const s16x8 ka1 = *(const s16x8*)&Ks[cur][o1];
      f32x4 a = {0.f, 0.f, 0.f, 0.f};
      a = __builtin_amdgcn_mfma_f32_16x16x32_bf16(ka0, qa00, a, 0, 0, 0);
      a = __builtin_amdgcn_mfma_f32_16x16x32_bf16(ka1, qa01, a, 0, 0, 0);
      a = __builtin_amdgcn_mfma_f32_16x16x32_bf16(ka0, qa10, a, 0, 0, 0);
      a = __builtin_amdgcn_mfma_f32_16x16x32_bf16(ka1, qa11, a, 0, 0, 0);
      sc[n] = a;
    }

    // ---- online softmax: all 16 scores of q=lq are in-lane ----
    float pm = sc[0][0];
#pragma unroll
    for (int n = 0; n < 4; ++n)
#pragma unroll
      for (int rg = 0; rg < 4; ++rg) pm = fmaxf(pm, sc[n][rg]);
    pm = fmaxf(pm, __shfl_xor(pm, 16, 64));
    pm = fmaxf(pm, __shfl_xor(pm, 32, 64));
    const float mn = fmaxf(mrun, pm);
    const float corr = exp2f(mrun - mn);
    mrun = mn;
    float pr[4][4];
    float rs = 0.f;
#pragma unroll
    for (int n = 0; n < 4; ++n)
#pragma unroll
      for (int rg = 0; rg < 4; ++rg) {
        pr[n][rg] = exp2f(sc[n][rg] - mn);
        rs += pr[n][rg];
      }
    rs += __shfl_xor(rs, 16, 64);
    rs += __shfl_xor(rs, 32, 64);
    lrun = lrun * corr + rs;
#pragma unroll
    for (int m = 0; m < 4; ++m) o[m] *= corr;

    // ---- P -> bf16 B-fragments, pure in-register (8 cvt_pk) ----
    uint32_t u[8];
#pragma unroll
    for (int n = 0; n < 4; ++n) {
      asm("v_cvt_pk_bf16_f32 %0, %1, %2"
          : "=v"(u[2 * n]) : "v"(pr[n][0]), "v"(pr[n][1]));
      asm("v_cvt_pk_bf16_f32 %0, %1, %2"
          : "=v"(u[2 * n + 1]) : "v"(pr[n][2]), "v"(pr[n][3]));
    }
    union { uint32_t uw[4]; s16x8 v; } p0, p1;
    p0.uw[0] = u[0]; p0.uw[1] = u[1]; p0.uw[2] = u[2]; p0.uw[3] = u[3];
    p1.uw[0] = u[4]; p1.uw[1] = u[5]; p1.uw[2] = u[6]; p1.uw[3] = u[7];

    // ---- PV swapped: o[m] = ctx^T[16m+4g+rg][lq] ----
#pragma unroll
    for (int m = 0; m < 4; ++m) {
      const int row = (m << 4) | lq;
      const int o0 = (row << 6) | (((g + 0) ^ (row & 7)) << 3);
      const int o1 = (row << 6) | (((g + 4) ^ (row & 7)) << 3);
      const s16x8 va0 = *(const s16x8*)&Vs[cur][o0];
      const s16x8 va1 = *(const s16x8*)&Vs[cur][o1];
      o[m] = __builtin_amdgcn_mfma_f32_16x16x32_bf16(va0, p0.v, o[m], 0, 0, 0);
      o[m] = __builtin_amdgcn_mfma_f32_16x16x32_bf16(va1, p1.v, o[m], 0, 0, 0);
    }

    // ---- stage next tile into other buffer ----
    if (kt + 1 < 64) {
      const int nx = cur ^ 1;
      *(float4*)&Ks[nx][kw0] = sk0;
      *(float4*)&Ks[nx][kw1] = sk1;
      union { float4 f; ushort4 h4[2]; } va, vb;
      va.f = sv0; vb.f = sv1;
      *(ushort4*)&Vs[nx][vw[0][0]] = va.h4[0];
      *(ushort4*)&Vs[nx][vw[0][1]] = va.h4[1];
      *(ushort4*)&Vs[nx][vw[1][0]] = vb.h4[0];
      *(ushort4*)&Vs[nx][vw[1][1]] = vb.h4[1];
    }
    __syncthreads();
  }

  // epilogue: ctx[s0+16w+lq][h*64 + 16m+4g+rg] = o[m][rg]/lrun (float4 packs)
  const float inv = 1.0f / lrun;
  float* crow = ctx + (size_t)(s0 + (w << 4) + lq) * DMODEL + (h << 6) + (g << 2);
#pragma unroll
  for (int m = 0; m < 4; ++m) {
    float4 res;
    res.x = o[m][0] * inv; res.y = o[m][1] * inv;
    res.z = o[m][2] * inv; res.w = o[m][3] * inv;
    *(float4*)(crow + (m << 4)) = res;
  }
}

extern "C" void kernel_launch(void* const* d_in, const int* in_sizes, int n_in,
                              void* d_out, int out_size, void* d_ws, size_t ws_size,
                              hipStream_t stream) {
  const float* x    = (const float*)d_in[0];
  const float* Wqkv = (const float*)d_in[1];
  const float* bqkv = (const float*)d_in[2];
  const float* Wout = (const float*)d_in[3];
  const float* bout = (const float*)d_in[4];
  float* out = (float*)d_out;

  const size_t NQ = (size_t)NH * S_LEN * HD;   // 3,145,728
  char* base = (char*)d_ws;
  ushort* qh = (ushort*)base;
  ushort* ql = qh + NQ;
  ushort* kh = ql + NQ;
  ushort* vt = kh + NQ;
  float* cx = (float*)(vt + NQ);                       // [S][D] fp32
  float* ct = cx + (size_t)S_LEN * DMODEL;
  float* st = ct + (size_t)S_LEN * HD;
  ushort* Wth = (ushort*)(st + (size_t)S_LEN * HD);    // [2304][768]
  ushort* Wtl = Wth + (size_t)3 * DMODEL * DMODEL;
  ushort* Woth = Wtl + (size_t)3 * DMODEL * DMODEL;    // [768][768]
  ushort* Wotl = Woth + (size_t)DMODEL * DMODEL;

  k_build_trig<<<dim3(S_LEN), dim3(64), 0, stream>>>(ct, st);
  k_tsplit<<<dim3(3 * DMODEL / 32, DMODEL / 32), dim3(256), 0, stream>>>(
      Wqkv, Wth, Wtl, DMODEL, 3 * DMODEL);
  k_tsplit<<<dim3(DMODEL / 32, DMODEL / 32), dim3(256), 0, stream>>>(
      Wout, Woth, Wotl, DMODEL, DMODEL);
  k_gemm_split<0><<<dim3(3 * DMODEL / 128, S_LEN / 128), dim3(256), 0, stream>>>(
      x, Wth, Wtl, bqkv, ct, st, qh, ql, kh, vt, nullptr);
  k_attn_mfma<<<dim3(S_LEN / 64, NH), dim3(256), 0, stream>>>(qh, ql, kh, vt, cx);
  k_gemm_split<1><<<dim3(DMODEL / 128, S_LEN / 128), dim3(256), 0, stream>>>(
      cx, Woth, Wotl, bout, nullptr, nullptr,
      nullptr, nullptr, nullptr, nullptr, out);
}

// Round 5
// 250.494 us; speedup vs baseline: 9.5313x; 1.0788x over previous
//
#include <hip/hip_runtime.h>
#include <hip/hip_bf16.h>
#include <math.h>

#define S_LEN 4096
#define DMODEL 768
#define NH 12
#define HD 64
#define BK 32

using f32x4 = __attribute__((ext_vector_type(4))) float;
using s16x8 = __attribute__((ext_vector_type(8))) short;

__device__ inline ushort f2bf(float f) {
  union { float f; uint32_t u; } v; v.f = f;
  uint32_t r = v.u + 0x7fffu + ((v.u >> 16) & 1u);   // RTNE
  return (ushort)(r >> 16);
}
__device__ inline float bf2f(ushort u) {
  union { uint32_t u; float f; } v; v.u = ((uint32_t)u) << 16;
  return v.f;
}

// scale folded into q: 1/sqrt(64) * log2(e)  -> softmax uses exp2
#define QSCL 0.18033688011112042f
#define DEFER_THR 8.0f

// ---------------- RoPE trig table (double precision on device) ----------------
__global__ void k_build_trig(float* __restrict__ ct, float* __restrict__ st) {
  const int s = blockIdx.x;
  const int d = threadIdx.x;
  const int j = d & 31;
  const double inv = pow(10000.0, -(double)j / 32.0);
  const double a = (double)s * inv;
  ct[s * HD + d] = (float)cos(a);
  st[s * HD + d] = (float)sin(a);
}

// ---------------- elementwise fp32 -> bf16 hi/lo split ----------------------
__global__ __launch_bounds__(256) void k_splitf(
    const float* __restrict__ in, ushort* __restrict__ oh,
    ushort* __restrict__ ol, int n4) {
  const int i = blockIdx.x * 256 + threadIdx.x;
  if (i >= n4) return;
  const float4 v = ((const float4*)in)[i];
  ushort4 h, lo;
  h.x = f2bf(v.x); lo.x = f2bf(v.x - bf2f(h.x));
  h.y = f2bf(v.y); lo.y = f2bf(v.y - bf2f(h.y));
  h.z = f2bf(v.z); lo.z = f2bf(v.z - bf2f(h.z));
  h.w = f2bf(v.w); lo.w = f2bf(v.w - bf2f(h.w));
  ((ushort4*)oh)[i] = h;
  ((ushort4*)ol)[i] = lo;
}

// ---------------- transpose + hi/lo bf16 split: W[R][C] -> T[C][R] ----------
__global__ __launch_bounds__(256) void k_tsplit(
    const float* __restrict__ W, ushort* __restrict__ Th,
    ushort* __restrict__ Tl, int R, int C) {
  __shared__ float tile[32][33];
  const int tx = threadIdx.x & 31, ty = threadIdx.x >> 5;  // 32 x 8
  const int c0 = blockIdx.x * 32, r0 = blockIdx.y * 32;
#pragma unroll
  for (int i = 0; i < 4; ++i)
    tile[ty + 8 * i][tx] = W[(size_t)(r0 + ty + 8 * i) * C + c0 + tx];
  __syncthreads();
#pragma unroll
  for (int i = 0; i < 4; ++i) {
    const float v = tile[tx][ty + 8 * i];
    const ushort h = f2bf(v);
    const size_t off = (size_t)(c0 + ty + 8 * i) * R + r0 + tx;
    Th[off] = h;
    Tl[off] = f2bf(v - bf2f(h));
  }
}

// ---------------- split-bf16 MFMA GEMM, 128x128 tile, BK=32 ------------------
// A pre-split bf16 hi/lo [M][768]; B pre-split bf16 [N][768].
// EPI 0: qkv epilogue (bias + RoPE; q -> hi/lo, k -> hi only, V transposed)
// EPI 1: out epilogue (bias + fp32 store)
template <int EPI>
__global__ __launch_bounds__(256) void k_gemm_split(
    const ushort* __restrict__ Ah, const ushort* __restrict__ Al,
    const ushort* __restrict__ Bh, const ushort* __restrict__ Bl,
    const float* __restrict__ bias,
    const float* __restrict__ ct, const float* __restrict__ st,
    ushort* __restrict__ qh, ushort* __restrict__ ql,
    ushort* __restrict__ kh, ushort* __restrict__ vt,
    float* __restrict__ out) {
  __shared__ __align__(16) ushort sAh[128 * BK];
  __shared__ __align__(16) ushort sAl[128 * BK];
  __shared__ __align__(16) ushort sBh[128 * BK];
  __shared__ __align__(16) ushort sBl[128 * BK];

  const int t = threadIdx.x;
  const int w = t >> 6, l = t & 63, g = l >> 4, lq = l & 15;
  const int wm = w >> 1, wn = w & 1;
  const int m0 = blockIdx.y * 128, n0 = blockIdx.x * 128;

  f32x4 acc[4][4];
#pragma unroll
  for (int i = 0; i < 4; ++i)
#pragma unroll
    for (int j = 0; j < 4; ++j) acc[i][j] = (f32x4){0.f, 0.f, 0.f, 0.f};

  const int ra = t >> 1, ks = (t & 1) << 4;
  const ushort* Ahsrc = Ah + (size_t)(m0 + ra) * 768 + ks;
  const ushort* Alsrc = Al + (size_t)(m0 + ra) * 768 + ks;
  const ushort* Bhsrc = Bh + (size_t)(n0 + ra) * 768 + ks;
  const ushort* Blsrc = Bl + (size_t)(n0 + ra) * 768 + ks;
  const int c0 = (t & 1) << 1;
  const int wo0 = ra * BK + (((c0 + 0) ^ (ra & 3)) << 3);
  const int wo1 = ra * BK + (((c0 + 1) ^ (ra & 3)) << 3);

  float4 ah0 = *(const float4*)(Ahsrc);
  float4 ah1 = *(const float4*)(Ahsrc + 8);
  float4 al0 = *(const float4*)(Alsrc);
  float4 al1 = *(const float4*)(Alsrc + 8);
  float4 bh0 = *(const float4*)(Bhsrc);
  float4 bh1 = *(const float4*)(Bhsrc + 8);
  float4 bl0 = *(const float4*)(Blsrc);
  float4 bl1 = *(const float4*)(Blsrc + 8);

  for (int kt = 0; kt < 768 / BK; ++kt) {
    __syncthreads();
    *(float4*)&sAh[wo0] = ah0; *(float4*)&sAh[wo1] = ah1;
    *(float4*)&sAl[wo0] = al0; *(float4*)&sAl[wo1] = al1;
    *(float4*)&sBh[wo0] = bh0; *(float4*)&sBh[wo1] = bh1;
    *(float4*)&sBl[wo0] = bl0; *(float4*)&sBl[wo1] = bl1;
    __syncthreads();
    if (kt + 1 < 768 / BK) {
      const int ko = (kt + 1) * BK;
      ah0 = *(const float4*)(Ahsrc + ko);
      ah1 = *(const float4*)(Ahsrc + ko + 8);
      al0 = *(const float4*)(Alsrc + ko);
      al1 = *(const float4*)(Alsrc + ko + 8);
      bh0 = *(const float4*)(Bhsrc + ko);
      bh1 = *(const float4*)(Bhsrc + ko + 8);
      bl0 = *(const float4*)(Blsrc + ko);
      bl1 = *(const float4*)(Blsrc + ko + 8);
    }
    s16x8 af[4], alf[4];
#pragma unroll
    for (int mf = 0; mf < 4; ++mf) {
      const int arow = wm * 64 + mf * 16 + lq;
      const int off = arow * BK + ((g ^ (arow & 3)) << 3);
      af[mf] = *(const s16x8*)&sAh[off];
      alf[mf] = *(const s16x8*)&sAl[off];
    }
    __builtin_amdgcn_s_setprio(1);
#pragma unroll
    for (int nf = 0; nf < 4; ++nf) {
      const int brow = wn * 64 + nf * 16 + lq;
      const int off = brow * BK + ((g ^ (brow & 3)) << 3);
      const s16x8 bhf = *(const s16x8*)&sBh[off];
      const s16x8 blf = *(const s16x8*)&sBl[off];
#pragma unroll
      for (int mf = 0; mf < 4; ++mf) {
        acc[mf][nf] = __builtin_amdgcn_mfma_f32_16x16x32_bf16(af[mf], bhf, acc[mf][nf], 0, 0, 0);
        acc[mf][nf] = __builtin_amdgcn_mfma_f32_16x16x32_bf16(af[mf], blf, acc[mf][nf], 0, 0, 0);
        acc[mf][nf] = __builtin_amdgcn_mfma_f32_16x16x32_bf16(alf[mf], bhf, acc[mf][nf], 0, 0, 0);
      }
    }
    __builtin_amdgcn_s_setprio(0);
  }

  if (EPI == 0) {
    const int cidx = n0 / DMODEL;   // 0:q 1:k 2:v (block-uniform)
    if (cidx < 2) {
      ushort* dh = (cidx == 0) ? qh : kh;
      const float scl = (cidx == 0) ? QSCL : 1.0f;
#pragma unroll
      for (int nf = 0; nf < 4; ++nf) {
        const int n = n0 + wn * 64 + nf * 16 + lq;
        const int rem = n - cidx * DMODEL;
        const int hh = rem >> 6, d = rem & 63;
        const float sgn = (d & 1) ? 1.f : -1.f;
        const float bb = bias[n];
#pragma unroll
        for (int mf = 0; mf < 4; ++mf)
#pragma unroll
          for (int rg = 0; rg < 4; ++rg) {
            const int s = m0 + wm * 64 + mf * 16 + g * 4 + rg;
            const float v = acc[mf][nf][rg] + bb;
            const float vp = __shfl_xor(v, 1, 64);
            const float o = (v * ct[s * HD + d] + sgn * vp * st[s * HD + d]) * scl;
            const ushort hv = f2bf(o);
            const size_t off = (((size_t)hh * S_LEN + s) << 6) + d;
            dh[off] = hv;
            if (cidx == 0) ql[off] = f2bf(o - bf2f(hv));
          }
      }
    } else {
#pragma unroll
      for (int nf = 0; nf < 4; ++nf) {
        const int n = n0 + wn * 64 + nf * 16 + lq;
        const int rem = n - 2 * DMODEL;
        const int hh = rem >> 6, d = rem & 63;
        const float bb = bias[n];
#pragma unroll
        for (int mf = 0; mf < 4; ++mf) {
          union { ushort us[4]; ushort4 u4; } u;
#pragma unroll
          for (int rg = 0; rg < 4; ++rg) u.us[rg] = f2bf(acc[mf][nf][rg] + bb);
          const int sb = m0 + wm * 64 + mf * 16 + g * 4;
          *(ushort4*)(vt + ((size_t)hh * 64 + d) * S_LEN + sb) = u.u4;
        }
      }
    }
  } else {
#pragma unroll
    for (int nf = 0; nf < 4; ++nf) {
      const int n = n0 + wn * 64 + nf * 16 + lq;
      const float bb = bias[n];
#pragma unroll
      for (int mf = 0; mf < 4; ++mf)
#pragma unroll
        for (int rg = 0; rg < 4; ++rg) {
          const int s = m0 + wm * 64 + mf * 16 + g * 4 + rg;
          out[(size_t)s * DMODEL + n] = acc[mf][nf][rg] + bb;
        }
    }
  }
}

// ---------------- flash attention: swapped QK^T, dbuf LDS, in-reg P ----------
// grid (S/64, H), 256 threads = 4 waves; wave w owns q-rows s0+16w..+15.
// S^T = mfma(K, Q): lane (g,lq) holds S^T[k=16n+4g+rg][q=lq].
// V k-columns permuted in LDS so natural P^T register layout IS the PV
// B-fragment. Defer-max (THR=8): skipped tiles have zero shuffles.
// Epilogue emits ctx as bf16 hi/lo for the out-proj GEMM.
__global__ __launch_bounds__(256) void k_attn_mfma(
    const ushort* __restrict__ qh, const ushort* __restrict__ ql,
    const ushort* __restrict__ kh, const ushort* __restrict__ vt,
    ushort* __restrict__ cxh, ushort* __restrict__ cxl) {
  const int h = blockIdx.y;
  const int s0 = blockIdx.x << 6;
  const int t = threadIdx.x;
  const int w = t >> 6, l = t & 63, lq = l & 15, g = l >> 4;

  __shared__ __align__(16) ushort Ks[2][4096];   // [64 k][64 d], chunk-XOR swz
  __shared__ __align__(16) ushort Vs[2][4096];   // [64 d][64 k-permuted], swz

  s16x8 qa00, qa01, qa10, qa11;
  {
    const size_t qoff = ((size_t)h * S_LEN + s0 + (w << 4) + lq) * 64 + (g << 3);
    qa00 = *(const s16x8*)(qh + qoff);
    qa01 = *(const s16x8*)(qh + qoff + 32);
    qa10 = *(const s16x8*)(ql + qoff);
    qa11 = *(const s16x8*)(ql + qoff + 32);
  }

  f32x4 o[4];
#pragma unroll
  for (int m = 0; m < 4; ++m) o[m] = (f32x4){0.f, 0.f, 0.f, 0.f};
  float mrun = -3.0e30f, lrun = 0.f;   // lrun: per-lane partial (k-subset)

  const int r = t >> 2, c0 = (t & 3) << 1;
  const ushort* gk = kh + ((size_t)h * S_LEN + r) * 64 + (c0 << 3);
  const ushort* gv = vt + ((size_t)h * 64 + r) * S_LEN + (c0 << 3);
  const int kw0 = (r << 6) | ((c0 ^ (r & 7)) << 3);
  const int kw1 = (r << 6) | (((c0 + 1) ^ (r & 7)) << 3);
  int vw[2][2];
#pragma unroll
  for (int cc = 0; cc < 2; ++cc) {
    const int c = c0 + cc;
    const int k5 = c >> 2, k4 = (c >> 1) & 1, k3 = c & 1;
#pragma unroll
    for (int hh = 0; hh < 2; ++hh) {
      const int ch = 4 * k5 + 2 * k3 + hh;      // permuted chunk
      vw[cc][hh] = (r << 6) | ((ch ^ (r & 7)) << 3) | (k4 << 2);
    }
  }

  float4 sk0 = *(const float4*)(gk);
  float4 sk1 = *(const float4*)(gk + 8);
  float4 sv0 = *(const float4*)(gv);
  float4 sv1 = *(const float4*)(gv + 8);

  {
    *(float4*)&Ks[0][kw0] = sk0;
    *(float4*)&Ks[0][kw1] = sk1;
    union { float4 f; ushort4 h4[2]; } va, vb;
    va.f = sv0; vb.f = sv1;
    *(ushort4*)&Vs[0][vw[0][0]] = va.h4[0];
    *(ushort4*)&Vs[0][vw[0][1]] = va.h4[1];
    *(ushort4*)&Vs[0][vw[1][0]] = vb.h4[0];
    *(ushort4*)&Vs[0][vw[1][1]] = vb.h4[1];
  }
  __syncthreads();

  for (int kt = 0; kt < 64; ++kt) {
    const int cur = kt & 1;
    if (kt + 1 < 64) {
      const size_t go = (size_t)(kt + 1) << 12;
      const size_t gvo = (size_t)(kt + 1) << 6;
      sk0 = *(const float4*)(gk + go);
      sk1 = *(const float4*)(gk + go + 8);
      sv0 = *(const float4*)(gv + gvo);
      sv1 = *(const float4*)(gv + gvo + 8);
    }

    // ---- QK^T swapped ----
    f32x4 sc[4];
    __builtin_amdgcn_s_setprio(1);
#pragma unroll
    for (int n = 0; n < 4; ++n) {
      const int row = (n << 4) | lq;
      const int o0 = (row << 6) | (((g + 0) ^ (row & 7)) << 3);
      const int o1 = (row << 6) | (((g + 4) ^ (row & 7)) << 3);
      const s16x8 ka0 = *(const s16x8*)&Ks[cur][o0];
      const s16x8 ka1 = *(const s16x8*)&Ks[cur][o1];
      f32x4 a = {0.f, 0.f, 0.f, 0.f};
      a = __builtin_amdgcn_mfma_f32_16x16x32_bf16(ka0, qa00, a, 0, 0, 0);
      a = __builtin_amdgcn_mfma_f32_16x16x32_bf16(ka1, qa01, a, 0, 0, 0);
      a = __builtin_amdgcn_mfma_f32_16x16x32_bf16(ka0, qa10, a, 0, 0, 0);
      a = __builtin_amdgcn_mfma_f32_16x16x32_bf16(ka1, qa11, a, 0, 0, 0);
      sc[n] = a;
    }
    __builtin_amdgcn_s_setprio(0);

    // ---- online softmax with defer-max ----
    float pm = sc[0][0];
#pragma unroll
    for (int n = 0; n < 4; ++n)
#pragma unroll
      for (int rg = 0; rg < 4; ++rg) pm = fmaxf(pm, sc[n][rg]);
    if (!__all(pm - mrun <= DEFER_THR)) {   // rare: rescale
      pm = fmaxf(pm, __shfl_xor(pm, 16, 64));
      pm = fmaxf(pm, __shfl_xor(pm, 32, 64));
      const float mn = fmaxf(mrun, pm);
      const float corr = exp2f(mrun - mn);
      mrun = mn;
      lrun *= corr;
#pragma unroll
      for (int m = 0; m < 4; ++m) o[m] *= corr;
    }
    float pr[4][4];
    float rs = 0.f;
#pragma unroll
    for (int n = 0; n < 4; ++n)
#pragma unroll
      for (int rg = 0; rg < 4; ++rg) {
        pr[n][rg] = exp2f(sc[n][rg] - mrun);
        rs += pr[n][rg];
      }
    lrun += rs;

    // ---- P -> bf16 B-fragments, in-register ----
    uint32_t u[8];
#pragma unroll
    for (int n = 0; n < 4; ++n) {
      asm("v_cvt_pk_bf16_f32 %0, %1, %2"
          : "=v"(u[2 * n]) : "v"(pr[n][0]), "v"(pr[n][1]));
      asm("v_cvt_pk_bf16_f32 %0, %1, %2"
          : "=v"(u[2 * n + 1]) : "v"(pr[n][2]), "v"(pr[n][3]));
    }
    union { uint32_t uw[4]; s16x8 v; } p0, p1;
    p0.uw[0] = u[0]; p0.uw[1] = u[1]; p0.uw[2] = u[2]; p0.uw[3] = u[3];
    p1.uw[0] = u[4]; p1.uw[1] = u[5]; p1.uw[2] = u[6]; p1.uw[3] = u[7];

    // ---- PV swapped ----
    __builtin_amdgcn_s_setprio(1);
#pragma unroll
    for (int m = 0; m < 4; ++m) {
      const int row = (m << 4) | lq;
      const int o0 = (row << 6) | (((g + 0) ^ (row & 7)) << 3);
      const int o1 = (row << 6) | (((g + 4) ^ (row & 7)) << 3);
      const s16x8 va0 = *(const s16x8*)&Vs[cur][o0];
      const s16x8 va1 = *(const s16x8*)&Vs[cur][o1];
      o[m] = __builtin_amdgcn_mfma_f32_16x16x32_bf16(va0, p0.v, o[m], 0, 0, 0);
      o[m] = __builtin_amdgcn_mfma_f32_16x16x32_bf16(va1, p1.v, o[m], 0, 0, 0);
    }
    __builtin_amdgcn_s_setprio(0);

    if (kt + 1 < 64) {
      const int nx = cur ^ 1;
      *(float4*)&Ks[nx][kw0] = sk0;
      *(float4*)&Ks[nx][kw1] = sk1;
      union { float4 f; ushort4 h4[2]; } va, vb;
      va.f = sv0; vb.f = sv1;
      *(ushort4*)&Vs[nx][vw[0][0]] = va.h4[0];
      *(ushort4*)&Vs[nx][vw[0][1]] = va.h4[1];
      *(ushort4*)&Vs[nx][vw[1][0]] = vb.h4[0];
      *(ushort4*)&Vs[nx][vw[1][1]] = vb.h4[1];
    }
    __syncthreads();
  }

  // epilogue: finish deferred l-reduce, write ctx as bf16 hi/lo
  lrun += __shfl_xor(lrun, 16, 64);
  lrun += __shfl_xor(lrun, 32, 64);
  const float inv = 1.0f / lrun;
  const size_t rowoff = (size_t)(s0 + (w << 4) + lq) * DMODEL + (h << 6) + (g << 2);
  ushort* hrow = cxh + rowoff;
  ushort* lrow = cxl + rowoff;
#pragma unroll
  for (int m = 0; m < 4; ++m) {
    const float v0 = o[m][0] * inv, v1 = o[m][1] * inv;
    const float v2 = o[m][2] * inv, v3 = o[m][3] * inv;
    uint32_t h01, h23;
    asm("v_cvt_pk_bf16_f32 %0, %1, %2" : "=v"(h01) : "v"(v0), "v"(v1));
    asm("v_cvt_pk_bf16_f32 %0, %1, %2" : "=v"(h23) : "v"(v2), "v"(v3));
    const float r0 = __uint_as_float(h01 << 16);
    const float r1 = __uint_as_float(h01 & 0xffff0000u);
    const float r2 = __uint_as_float(h23 << 16);
    const float r3 = __uint_as_float(h23 & 0xffff0000u);
    uint32_t l01, l23;
    asm("v_cvt_pk_bf16_f32 %0, %1, %2" : "=v"(l01) : "v"(v0 - r0), "v"(v1 - r1));
    asm("v_cvt_pk_bf16_f32 %0, %1, %2" : "=v"(l23) : "v"(v2 - r2), "v"(v3 - r3));
    uint2 hq, lqv;
    hq.x = h01; hq.y = h23; lqv.x = l01; lqv.y = l23;
    *(uint2*)(hrow + (m << 4)) = hq;
    *(uint2*)(lrow + (m << 4)) = lqv;
  }
}

extern "C" void kernel_launch(void* const* d_in, const int* in_sizes, int n_in,
                              void* d_out, int out_size, void* d_ws, size_t ws_size,
                              hipStream_t stream) {
  const float* x    = (const float*)d_in[0];
  const float* Wqkv = (const float*)d_in[1];
  const float* bqkv = (const float*)d_in[2];
  const float* Wout = (const float*)d_in[3];
  const float* bout = (const float*)d_in[4];
  float* out = (float*)d_out;

  const size_t NQ = (size_t)NH * S_LEN * HD;   // 3,145,728
  const size_t ND = (size_t)S_LEN * DMODEL;    // 3,145,728
  char* base = (char*)d_ws;
  ushort* qh = (ushort*)base;
  ushort* ql = qh + NQ;
  ushort* kh = ql + NQ;
  ushort* vt = kh + NQ;
  ushort* xh = vt + NQ;          // [S][768] hi; reused as cxh after qkv GEMM
  ushort* xl = xh + ND;          // lo; reused as cxl
  float* ct = (float*)(xl + ND);
  float* st = ct + (size_t)S_LEN * HD;
  ushort* Wth = (ushort*)(st + (size_t)S_LEN * HD);    // [2304][768]
  ushort* Wtl = Wth + (size_t)3 * DMODEL * DMODEL;
  ushort* Woth = Wtl + (size_t)3 * DMODEL * DMODEL;    // [768][768]
  ushort* Wotl = Woth + (size_t)DMODEL * DMODEL;

  k_build_trig<<<dim3(S_LEN), dim3(64), 0, stream>>>(ct, st);
  k_tsplit<<<dim3(3 * DMODEL / 32, DMODEL / 32), dim3(256), 0, stream>>>(
      Wqkv, Wth, Wtl, DMODEL, 3 * DMODEL);
  k_tsplit<<<dim3(DMODEL / 32, DMODEL / 32), dim3(256), 0, stream>>>(
      Wout, Woth, Wotl, DMODEL, DMODEL);
  k_splitf<<<dim3((int)(ND / 4 / 256)), dim3(256), 0, stream>>>(
      x, xh, xl, (int)(ND / 4));
  k_gemm_split<0><<<dim3(3 * DMODEL / 128, S_LEN / 128), dim3(256), 0, stream>>>(
      xh, xl, Wth, Wtl, bqkv, ct, st, qh, ql, kh, vt, nullptr);
  k_attn_mfma<<<dim3(S_LEN / 64, NH), dim3(256), 0, stream>>>(
      qh, ql, kh, vt, xh, xl);
  k_gemm_split<1><<<dim3(DMODEL / 128, S_LEN / 128), dim3(256), 0, stream>>>(
      xh, xl, Woth, Wotl, bout, nullptr, nullptr,
      nullptr, nullptr, nullptr, nullptr, out);
}

// Round 6
// 229.390 us; speedup vs baseline: 10.4081x; 1.0920x over previous
//
#include <hip/hip_runtime.h>
#include <hip/hip_bf16.h>
#include <math.h>

#define S_LEN 4096
#define DMODEL 768
#define NH 12
#define HD 64

using f32x4 = __attribute__((ext_vector_type(4))) float;
using s16x8 = __attribute__((ext_vector_type(8))) short;

__device__ inline ushort f2bf(float f) {
  union { float f; uint32_t u; } v; v.f = f;
  uint32_t r = v.u + 0x7fffu + ((v.u >> 16) & 1u);   // RTNE
  return (ushort)(r >> 16);
}
__device__ inline float bf2f(ushort u) {
  union { uint32_t u; float f; } v; v.u = ((uint32_t)u) << 16;
  return v.f;
}

__device__ __forceinline__ void gload16(const ushort* g, ushort* l) {
  __builtin_amdgcn_global_load_lds(
      (const __attribute__((address_space(1))) unsigned int*)g,
      (__attribute__((address_space(3))) unsigned int*)l, 16, 0, 0);
}

// scale folded into q: 1/sqrt(64) * log2(e)  -> softmax uses exp2
#define QSCL 0.18033688011112042f
#define DEFER_THR 8.0f

// ---------------- RoPE trig table (double precision on device) ----------------
__global__ void k_build_trig(float* __restrict__ ct, float* __restrict__ st) {
  const int s = blockIdx.x;
  const int d = threadIdx.x;
  const int j = d & 31;
  const double inv = pow(10000.0, -(double)j / 32.0);
  const double a = (double)s * inv;
  ct[s * HD + d] = (float)cos(a);
  st[s * HD + d] = (float)sin(a);
}

// ---------------- elementwise fp32 -> bf16 hi/lo split ----------------------
__global__ __launch_bounds__(256) void k_splitf(
    const float* __restrict__ in, ushort* __restrict__ oh,
    ushort* __restrict__ ol, int n4) {
  const int i = blockIdx.x * 256 + threadIdx.x;
  if (i >= n4) return;
  const float4 v = ((const float4*)in)[i];
  ushort4 h, lo;
  h.x = f2bf(v.x); lo.x = f2bf(v.x - bf2f(h.x));
  h.y = f2bf(v.y); lo.y = f2bf(v.y - bf2f(h.y));
  h.z = f2bf(v.z); lo.z = f2bf(v.z - bf2f(h.z));
  h.w = f2bf(v.w); lo.w = f2bf(v.w - bf2f(h.w));
  ((ushort4*)oh)[i] = h;
  ((ushort4*)ol)[i] = lo;
}

// ---------------- transpose + hi/lo bf16 split: W[R][C] -> T[C][R] ----------
__global__ __launch_bounds__(256) void k_tsplit(
    const float* __restrict__ W, ushort* __restrict__ Th,
    ushort* __restrict__ Tl, int R, int C) {
  __shared__ float tile[32][33];
  const int tx = threadIdx.x & 31, ty = threadIdx.x >> 5;  // 32 x 8
  const int c0 = blockIdx.x * 32, r0 = blockIdx.y * 32;
#pragma unroll
  for (int i = 0; i < 4; ++i)
    tile[ty + 8 * i][tx] = W[(size_t)(r0 + ty + 8 * i) * C + c0 + tx];
  __syncthreads();
#pragma unroll
  for (int i = 0; i < 4; ++i) {
    const float v = tile[tx][ty + 8 * i];
    const ushort h = f2bf(v);
    const size_t off = (size_t)(c0 + ty + 8 * i) * R + r0 + tx;
    Th[off] = h;
    Tl[off] = f2bf(v - bf2f(h));
  }
}

// ---------------- split-bf16 MFMA GEMM, 128x128 tile, BK=64 ------------------
// Staging via global_load_lds (16B): swizzle baked into the per-lane GLOBAL
// source address, LDS dest linear (G21). Wave w stages buffer w.
// EPI 0: qkv epilogue (bias + RoPE; q -> hi/lo, k -> hi only, V transposed)
// EPI 1: out epilogue (bias + fp32 store)
template <int EPI>
__global__ __launch_bounds__(256) void k_gemm_split(
    const ushort* __restrict__ Ah, const ushort* __restrict__ Al,
    const ushort* __restrict__ Bh, const ushort* __restrict__ Bl,
    const float* __restrict__ bias,
    const float* __restrict__ ct, const float* __restrict__ st,
    ushort* __restrict__ qh, ushort* __restrict__ ql,
    ushort* __restrict__ kh, ushort* __restrict__ vt,
    float* __restrict__ out) {
  // SS: [buf][128 rows][64 k] shorts; buf 0:Ah 1:Al 2:Bh 3:Bl (8192 shorts each)
  __shared__ __align__(16) ushort SS[4 * 8192];

  const int t = threadIdx.x;
  const int w = t >> 6, l = t & 63, g = l >> 4, lq = l & 15;
  const int wm = w >> 1, wn = w & 1;
  const int m0 = blockIdx.y * 128, n0 = blockIdx.x * 128;

  f32x4 acc[4][4];
#pragma unroll
  for (int i = 0; i < 4; ++i)
#pragma unroll
    for (int j = 0; j < 4; ++j) acc[i][j] = (f32x4){0.f, 0.f, 0.f, 0.f};

  // staging source: per-lane global addr with swizzle; LDS dest linear
  const ushort* gsrc =
      (w == 0) ? Ah + (size_t)m0 * 768 :
      (w == 1) ? Al + (size_t)m0 * 768 :
      (w == 2) ? Bh + (size_t)n0 * 768 :
                 Bl + (size_t)n0 * 768;
  const int grow = l >> 3, gch = l & 7;            // 8 rows x 8 chunks per inst
  gsrc += (size_t)grow * 768 + ((gch ^ grow) << 3);
  ushort* lbase = SS + w * 8192;                    // +i*512 per inst

  // fragment read bases: one vaddr per (operand, k-half); rest are literals
  const ushort* rdA[2], * rdB[2];
#pragma unroll
  for (int kk = 0; kk < 2; ++kk) {
    rdA[kk] = SS + wm * 4096 + lq * 64 + ((((kk << 2) | g) ^ (lq & 7)) << 3);
    rdB[kk] = SS + 16384 + wn * 4096 + lq * 64 + ((((kk << 2) | g) ^ (lq & 7)) << 3);
  }

  for (int kt = 0; kt < 768 / 64; ++kt) {
    __syncthreads();               // prior tile's reads complete
#pragma unroll
    for (int i = 0; i < 16; ++i)
      gload16(gsrc + (size_t)i * (8 * 768) + kt * 64, lbase + i * 512);
    __syncthreads();               // drain loads -> tile ready
#pragma unroll
    for (int kk = 0; kk < 2; ++kk) {
      s16x8 ah[4], al4[4];
#pragma unroll
      for (int mf = 0; mf < 4; ++mf) {
        ah[mf]  = *(const s16x8*)(rdA[kk] + mf * 1024);
        al4[mf] = *(const s16x8*)(rdA[kk] + mf * 1024 + 8192);
      }
      __builtin_amdgcn_s_setprio(1);
#pragma unroll
      for (int nf = 0; nf < 4; ++nf) {
        const s16x8 bhf = *(const s16x8*)(rdB[kk] + nf * 1024);
        const s16x8 blf = *(const s16x8*)(rdB[kk] + nf * 1024 + 8192);
#pragma unroll
        for (int mf = 0; mf < 4; ++mf) {
          acc[mf][nf] = __builtin_amdgcn_mfma_f32_16x16x32_bf16(ah[mf], bhf, acc[mf][nf], 0, 0, 0);
          acc[mf][nf] = __builtin_amdgcn_mfma_f32_16x16x32_bf16(ah[mf], blf, acc[mf][nf], 0, 0, 0);
          acc[mf][nf] = __builtin_amdgcn_mfma_f32_16x16x32_bf16(al4[mf], bhf, acc[mf][nf], 0, 0, 0);
        }
      }
      __builtin_amdgcn_s_setprio(0);
    }
  }

  if (EPI == 0) {
    const int cidx = n0 / DMODEL;   // 0:q 1:k 2:v (block-uniform)
    if (cidx < 2) {
      ushort* dh = (cidx == 0) ? qh : kh;
      const float scl = (cidx == 0) ? QSCL : 1.0f;
#pragma unroll
      for (int nf = 0; nf < 4; ++nf) {
        const int n = n0 + wn * 64 + nf * 16 + lq;
        const int rem = n - cidx * DMODEL;
        const int hh = rem >> 6, d = rem & 63;
        const float sgn = (d & 1) ? 1.f : -1.f;
        const float bb = bias[n];
#pragma unroll
        for (int mf = 0; mf < 4; ++mf)
#pragma unroll
          for (int rg = 0; rg < 4; ++rg) {
            const int s = m0 + wm * 64 + mf * 16 + g * 4 + rg;
            const float v = acc[mf][nf][rg] + bb;
            const float vp = __shfl_xor(v, 1, 64);
            const float o = (v * ct[s * HD + d] + sgn * vp * st[s * HD + d]) * scl;
            const ushort hv = f2bf(o);
            const size_t off = (((size_t)hh * S_LEN + s) << 6) + d;
            dh[off] = hv;
            if (cidx == 0) ql[off] = f2bf(o - bf2f(hv));
          }
      }
    } else {
#pragma unroll
      for (int nf = 0; nf < 4; ++nf) {
        const int n = n0 + wn * 64 + nf * 16 + lq;
        const int rem = n - 2 * DMODEL;
        const int hh = rem >> 6, d = rem & 63;
        const float bb = bias[n];
#pragma unroll
        for (int mf = 0; mf < 4; ++mf) {
          union { ushort us[4]; ushort4 u4; } u;
#pragma unroll
          for (int rg = 0; rg < 4; ++rg) u.us[rg] = f2bf(acc[mf][nf][rg] + bb);
          const int sb = m0 + wm * 64 + mf * 16 + g * 4;
          *(ushort4*)(vt + ((size_t)hh * 64 + d) * S_LEN + sb) = u.u4;
        }
      }
    }
  } else {
#pragma unroll
    for (int nf = 0; nf < 4; ++nf) {
      const int n = n0 + wn * 64 + nf * 16 + lq;
      const float bb = bias[n];
#pragma unroll
      for (int mf = 0; mf < 4; ++mf)
#pragma unroll
        for (int rg = 0; rg < 4; ++rg) {
          const int s = m0 + wm * 64 + mf * 16 + g * 4 + rg;
          out[(size_t)s * DMODEL + n] = acc[mf][nf][rg] + bb;
        }
    }
  }
}

// ---------------- flash attention: swapped QK^T, dbuf LDS, in-reg P ----------
// grid (S/64, H), 256 threads = 4 waves; wave w owns q-rows s0+16w..+15.
// Unrolled x2: all LDS addresses are loop-invariant vaddrs + literal offsets.
__global__ __launch_bounds__(256) void k_attn_mfma(
    const ushort* __restrict__ qh, const ushort* __restrict__ ql,
    const ushort* __restrict__ kh, const ushort* __restrict__ vt,
    ushort* __restrict__ cxh, ushort* __restrict__ cxl) {
  const int h = blockIdx.y;
  const int s0 = blockIdx.x << 6;
  const int t = threadIdx.x;
  const int w = t >> 6, l = t & 63, lq = l & 15, g = l >> 4;

  __shared__ __align__(16) ushort Ks0[2 * 4096];  // [buf][64 k][64 d], swz
  __shared__ __align__(16) ushort Vs0[2 * 4096];  // [buf][64 d][64 k-perm], swz

  s16x8 qa00, qa01, qa10, qa11;
  {
    const size_t qoff = ((size_t)h * S_LEN + s0 + (w << 4) + lq) * 64 + (g << 3);
    qa00 = *(const s16x8*)(qh + qoff);
    qa01 = *(const s16x8*)(qh + qoff + 32);
    qa10 = *(const s16x8*)(ql + qoff);
    qa11 = *(const s16x8*)(ql + qoff + 32);
  }

  f32x4 o[4];
#pragma unroll
  for (int m = 0; m < 4; ++m) o[m] = (f32x4){0.f, 0.f, 0.f, 0.f};
  float mrun = -3.0e30f, lrun = 0.f;

  // ---- loop-invariant LDS addresses ----
  // read bases (lane-dependent swizzle; n/m/cur become literal offsets)
  const int b0 = (lq << 6) | ((g ^ (lq & 7)) << 3);
  const int b1 = (lq << 6) | (((g + 4) ^ (lq & 7)) << 3);
  const ushort* kr0 = Ks0 + b0;
  const ushort* kr1 = Ks0 + b1;
  const ushort* vr0 = Vs0 + b0;
  const ushort* vr1 = Vs0 + b1;
  // staging bases
  const int r = t >> 2, c0 = (t & 3) << 1;
  const ushort* gk = kh + ((size_t)h * S_LEN + r) * 64 + (c0 << 3);
  const ushort* gv = vt + ((size_t)h * 64 + r) * S_LEN + (c0 << 3);
  ushort* kwp0 = Ks0 + ((r << 6) | ((c0 ^ (r & 7)) << 3));
  ushort* kwp1 = Ks0 + ((r << 6) | (((c0 + 1) ^ (r & 7)) << 3));
  ushort* vwp[2][2];
#pragma unroll
  for (int cc = 0; cc < 2; ++cc) {
    const int c = c0 + cc;
    const int k5 = c >> 2, k4 = (c >> 1) & 1, k3 = c & 1;
#pragma unroll
    for (int hh = 0; hh < 2; ++hh) {
      const int ch = 4 * k5 + 2 * k3 + hh;      // permuted chunk
      vwp[cc][hh] = Vs0 + ((r << 6) | ((ch ^ (r & 7)) << 3) | (k4 << 2));
    }
  }

  float4 sk0, sk1, sv0, sv1;
  // prologue: tile 0 -> buf 0
  sk0 = *(const float4*)(gk); sk1 = *(const float4*)(gk + 8);
  sv0 = *(const float4*)(gv); sv1 = *(const float4*)(gv + 8);
  gk += 4096; gv += 64;
  {
    *(float4*)(kwp0) = sk0;
    *(float4*)(kwp1) = sk1;
    union { float4 f; ushort4 h4[2]; } va, vb;
    va.f = sv0; vb.f = sv1;
    *(ushort4*)(vwp[0][0]) = va.h4[0];
    *(ushort4*)(vwp[0][1]) = va.h4[1];
    *(ushort4*)(vwp[1][0]) = vb.h4[0];
    *(ushort4*)(vwp[1][1]) = vb.h4[1];
  }
  __syncthreads();

  auto body = [&](const int CUR, const int NX, bool pref) {
    if (pref) {
      sk0 = *(const float4*)(gk); sk1 = *(const float4*)(gk + 8);
      sv0 = *(const float4*)(gv); sv1 = *(const float4*)(gv + 8);
      gk += 4096; gv += 64;
    }
    // ---- QK^T swapped ----
    f32x4 sc[4];
    __builtin_amdgcn_s_setprio(1);
#pragma unroll
    for (int n = 0; n < 4; ++n) {
      const s16x8 ka0 = *(const s16x8*)(kr0 + CUR * 4096 + (n << 10));
      const s16x8 ka1 = *(const s16x8*)(kr1 + CUR * 4096 + (n << 10));
      f32x4 a = {0.f, 0.f, 0.f, 0.f};
      a = __builtin_amdgcn_mfma_f32_16x16x32_bf16(ka0, qa00, a, 0, 0, 0);
      a = __builtin_amdgcn_mfma_f32_16x16x32_bf16(ka1, qa01, a, 0, 0, 0);
      a = __builtin_amdgcn_mfma_f32_16x16x32_bf16(ka0, qa10, a, 0, 0, 0);
      a = __builtin_amdgcn_mfma_f32_16x16x32_bf16(ka1, qa11, a, 0, 0, 0);
      sc[n] = a;
    }
    __builtin_amdgcn_s_setprio(0);

    // ---- online softmax with defer-max ----
    float pm = sc[0][0];
#pragma unroll
    for (int n = 0; n < 4; ++n)
#pragma unroll
      for (int rg = 0; rg < 4; ++rg) pm = fmaxf(pm, sc[n][rg]);
    if (!__all(pm - mrun <= DEFER_THR)) {
      pm = fmaxf(pm, __shfl_xor(pm, 16, 64));
      pm = fmaxf(pm, __shfl_xor(pm, 32, 64));
      const float mn = fmaxf(mrun, pm);
      const float corr = exp2f(mrun - mn);
      mrun = mn;
      lrun *= corr;
#pragma unroll
      for (int m = 0; m < 4; ++m) o[m] *= corr;
    }
    float pr[4][4];
    float rs = 0.f;
#pragma unroll
    for (int n = 0; n < 4; ++n)
#pragma unroll
      for (int rg = 0; rg < 4; ++rg) {
        pr[n][rg] = exp2f(sc[n][rg] - mrun);
        rs += pr[n][rg];
      }
    lrun += rs;

    // ---- P -> bf16 B-fragments, in-register ----
    uint32_t u[8];
#pragma unroll
    for (int n = 0; n < 4; ++n) {
      asm("v_cvt_pk_bf16_f32 %0, %1, %2"
          : "=v"(u[2 * n]) : "v"(pr[n][0]), "v"(pr[n][1]));
      asm("v_cvt_pk_bf16_f32 %0, %1, %2"
          : "=v"(u[2 * n + 1]) : "v"(pr[n][2]), "v"(pr[n][3]));
    }
    union { uint32_t uw[4]; s16x8 v; } p0, p1;
    p0.uw[0] = u[0]; p0.uw[1] = u[1]; p0.uw[2] = u[2]; p0.uw[3] = u[3];
    p1.uw[0] = u[4]; p1.uw[1] = u[5]; p1.uw[2] = u[6]; p1.uw[3] = u[7];

    // ---- PV swapped ----
    __builtin_amdgcn_s_setprio(1);
#pragma unroll
    for (int m = 0; m < 4; ++m) {
      const s16x8 va0 = *(const s16x8*)(vr0 + CUR * 4096 + (m << 10));
      const s16x8 va1 = *(const s16x8*)(vr1 + CUR * 4096 + (m << 10));
      o[m] = __builtin_amdgcn_mfma_f32_16x16x32_bf16(va0, p0.v, o[m], 0, 0, 0);
      o[m] = __builtin_amdgcn_mfma_f32_16x16x32_bf16(va1, p1.v, o[m], 0, 0, 0);
    }
    __builtin_amdgcn_s_setprio(0);

    if (pref) {
      *(float4*)(kwp0 + NX * 4096) = sk0;
      *(float4*)(kwp1 + NX * 4096) = sk1;
      union { float4 f; ushort4 h4[2]; } va, vb;
      va.f = sv0; vb.f = sv1;
      *(ushort4*)(vwp[0][0] + NX * 4096) = va.h4[0];
      *(ushort4*)(vwp[0][1] + NX * 4096) = va.h4[1];
      *(ushort4*)(vwp[1][0] + NX * 4096) = vb.h4[0];
      *(ushort4*)(vwp[1][1] + NX * 4096) = vb.h4[1];
    }
    __syncthreads();
  };

  for (int p = 0; p < 32; ++p) {
    body(0, 1, true);        // kt = 2p   (tile 2p+1 always exists)
    body(1, 0, p < 31);      // kt = 2p+1 (tile 2p+2 exists iff p<31)
  }

  // epilogue: finish deferred l-reduce, write ctx as bf16 hi/lo
  lrun += __shfl_xor(lrun, 16, 64);
  lrun += __shfl_xor(lrun, 32, 64);
  const float inv = 1.0f / lrun;
  const size_t rowoff = (size_t)(s0 + (w << 4) + lq) * DMODEL + (h << 6) + (g << 2);
  ushort* hrow = cxh + rowoff;
  ushort* lrow = cxl + rowoff;
#pragma unroll
  for (int m = 0; m < 4; ++m) {
    const float v0 = o[m][0] * inv, v1 = o[m][1] * inv;
    const float v2 = o[m][2] * inv, v3 = o[m][3] * inv;
    uint32_t h01, h23;
    asm("v_cvt_pk_bf16_f32 %0, %1, %2" : "=v"(h01) : "v"(v0), "v"(v1));
    asm("v_cvt_pk_bf16_f32 %0, %1, %2" : "=v"(h23) : "v"(v2), "v"(v3));
    const float r0 = __uint_as_float(h01 << 16);
    const float r1 = __uint_as_float(h01 & 0xffff0000u);
    const float r2 = __uint_as_float(h23 << 16);
    const float r3 = __uint_as_float(h23 & 0xffff0000u);
    uint32_t l01, l23;
    asm("v_cvt_pk_bf16_f32 %0, %1, %2" : "=v"(l01) : "v"(v0 - r0), "v"(v1 - r1));
    asm("v_cvt_pk_bf16_f32 %0, %1, %2" : "=v"(l23) : "v"(v2 - r2), "v"(v3 - r3));
    uint2 hq, lqv;
    hq.x = h01; hq.y = h23; lqv.x = l01; lqv.y = l23;
    *(uint2*)(hrow + (m << 4)) = hq;
    *(uint2*)(lrow + (m << 4)) = lqv;
  }
}

extern "C" void kernel_launch(void* const* d_in, const int* in_sizes, int n_in,
                              void* d_out, int out_size, void* d_ws, size_t ws_size,
                              hipStream_t stream) {
  const float* x    = (const float*)d_in[0];
  const float* Wqkv = (const float*)d_in[1];
  const float* bqkv = (const float*)d_in[2];
  const float* Wout = (const float*)d_in[3];
  const float* bout = (const float*)d_in[4];
  float* out = (float*)d_out;

  const size_t NQ = (size_t)NH * S_LEN * HD;   // 3,145,728
  const size_t ND = (size_t)S_LEN * DMODEL;    // 3,145,728
  char* base = (char*)d_ws;
  ushort* qh = (ushort*)base;
  ushort* ql = qh + NQ;
  ushort* kh = ql + NQ;
  ushort* vt = kh + NQ;
  ushort* xh = vt + NQ;          // [S][768] hi; reused as cxh after qkv GEMM
  ushort* xl = xh + ND;          // lo; reused as cxl
  float* ct = (float*)(xl + ND);
  float* st = ct + (size_t)S_LEN * HD;
  ushort* Wth = (ushort*)(st + (size_t)S_LEN * HD);    // [2304][768]
  ushort* Wtl = Wth + (size_t)3 * DMODEL * DMODEL;
  ushort* Woth = Wtl + (size_t)3 * DMODEL * DMODEL;    // [768][768]
  ushort* Wotl = Woth + (size_t)DMODEL * DMODEL;

  k_build_trig<<<dim3(S_LEN), dim3(64), 0, stream>>>(ct, st);
  k_tsplit<<<dim3(3 * DMODEL / 32, DMODEL / 32), dim3(256), 0, stream>>>(
      Wqkv, Wth, Wtl, DMODEL, 3 * DMODEL);
  k_tsplit<<<dim3(DMODEL / 32, DMODEL / 32), dim3(256), 0, stream>>>(
      Wout, Woth, Wotl, DMODEL, DMODEL);
  k_splitf<<<dim3((int)(ND / 4 / 256)), dim3(256), 0, stream>>>(
      x, xh, xl, (int)(ND / 4));
  k_gemm_split<0><<<dim3(3 * DMODEL / 128, S_LEN / 128), dim3(256), 0, stream>>>(
      xh, xl, Wth, Wtl, bqkv, ct, st, qh, ql, kh, vt, nullptr);
  k_attn_mfma<<<dim3(S_LEN / 64, NH), dim3(256), 0, stream>>>(
      qh, ql, kh, vt, xh, xl);
  k_gemm_split<1><<<dim3(DMODEL / 128, S_LEN / 128), dim3(256), 0, stream>>>(
      xh, xl, Woth, Wotl, bout, nullptr, nullptr,
      nullptr, nullptr, nullptr, nullptr, out);
}